// Round 1
// baseline (1488.817 us; speedup 1.0000x reference)
//
#include <hip/hip_runtime.h>
#include <math.h>

#define BATCH 2
#define S_LEN 2048
#define DMODEL 1024
#define NH 16
#define HDIM 64
#define SCALE 0.125f

// ---------------- SGEMM config: C[M,N] = A[M,K] * W[N,K]^T + bias ----------
#define BM 128
#define BN 128
#define BK 16

// QKV projection: x[4096,1024] @ qkv_w[3072,1024]^T + b -> scatter to Q/K/V [B,H,S,HD]
__global__ __launch_bounds__(256) void qkv_gemm_kernel(
    const float* __restrict__ x, const float* __restrict__ w,
    const float* __restrict__ bias, float* __restrict__ Q,
    float* __restrict__ K, float* __restrict__ V) {
  __shared__ float As[BK][BM + 8];
  __shared__ float Bs[BK][BN + 8];
  const int tid = threadIdx.x;
  const int tx = tid & 15, ty = tid >> 4;
  const int m0 = blockIdx.x * BM, n0 = blockIdx.y * BN;
  float acc[8][8] = {};
  for (int k0 = 0; k0 < DMODEL; k0 += BK) {
#pragma unroll
    for (int l = 0; l < 2; ++l) {
      int idx = tid + l * 256;
      int mm = idx >> 2, ks = (idx & 3) << 2;
      float4 v4 = *(const float4*)(x + (size_t)(m0 + mm) * DMODEL + k0 + ks);
      As[ks + 0][mm] = v4.x; As[ks + 1][mm] = v4.y;
      As[ks + 2][mm] = v4.z; As[ks + 3][mm] = v4.w;
    }
#pragma unroll
    for (int l = 0; l < 2; ++l) {
      int idx = tid + l * 256;
      int nn = idx >> 2, ks = (idx & 3) << 2;
      float4 v4 = *(const float4*)(w + (size_t)(n0 + nn) * DMODEL + k0 + ks);
      Bs[ks + 0][nn] = v4.x; Bs[ks + 1][nn] = v4.y;
      Bs[ks + 2][nn] = v4.z; Bs[ks + 3][nn] = v4.w;
    }
    __syncthreads();
#pragma unroll
    for (int kk = 0; kk < BK; ++kk) {
      float a[8], b[8];
      *(float4*)&a[0] = *(const float4*)&As[kk][ty * 8];
      *(float4*)&a[4] = *(const float4*)&As[kk][ty * 8 + 4];
      *(float4*)&b[0] = *(const float4*)&Bs[kk][tx * 8];
      *(float4*)&b[4] = *(const float4*)&Bs[kk][tx * 8 + 4];
#pragma unroll
      for (int i = 0; i < 8; ++i)
#pragma unroll
        for (int j = 0; j < 8; ++j) acc[i][j] = fmaf(a[i], b[j], acc[i][j]);
    }
    __syncthreads();
  }
#pragma unroll
  for (int i = 0; i < 8; ++i) {
    int m = m0 + ty * 8 + i;
    int bb = m >> 11, s = m & (S_LEN - 1);
#pragma unroll
    for (int j = 0; j < 8; ++j) {
      int e = n0 + tx * 8 + j;
      float val = acc[i][j] + bias[e];
      int h = e / 192;
      int r = e - h * 192;
      int d = r & 63;
      size_t off = (((size_t)(bb * NH + h) * S_LEN) + s) * HDIM + d;
      if (r < 64) Q[off] = val;
      else if (r < 128) K[off] = val;
      else V[off] = val;
    }
  }
}

// Output projection: values[4096,1024] @ o_w[1024,1024]^T + o_b -> out
__global__ __launch_bounds__(256) void o_gemm_kernel(
    const float* __restrict__ A, const float* __restrict__ w,
    const float* __restrict__ bias, float* __restrict__ out) {
  __shared__ float As[BK][BM + 8];
  __shared__ float Bs[BK][BN + 8];
  const int tid = threadIdx.x;
  const int tx = tid & 15, ty = tid >> 4;
  const int m0 = blockIdx.x * BM, n0 = blockIdx.y * BN;
  float acc[8][8] = {};
  for (int k0 = 0; k0 < DMODEL; k0 += BK) {
#pragma unroll
    for (int l = 0; l < 2; ++l) {
      int idx = tid + l * 256;
      int mm = idx >> 2, ks = (idx & 3) << 2;
      float4 v4 = *(const float4*)(A + (size_t)(m0 + mm) * DMODEL + k0 + ks);
      As[ks + 0][mm] = v4.x; As[ks + 1][mm] = v4.y;
      As[ks + 2][mm] = v4.z; As[ks + 3][mm] = v4.w;
    }
#pragma unroll
    for (int l = 0; l < 2; ++l) {
      int idx = tid + l * 256;
      int nn = idx >> 2, ks = (idx & 3) << 2;
      float4 v4 = *(const float4*)(w + (size_t)(n0 + nn) * DMODEL + k0 + ks);
      Bs[ks + 0][nn] = v4.x; Bs[ks + 1][nn] = v4.y;
      Bs[ks + 2][nn] = v4.z; Bs[ks + 3][nn] = v4.w;
    }
    __syncthreads();
#pragma unroll
    for (int kk = 0; kk < BK; ++kk) {
      float a[8], b[8];
      *(float4*)&a[0] = *(const float4*)&As[kk][ty * 8];
      *(float4*)&a[4] = *(const float4*)&As[kk][ty * 8 + 4];
      *(float4*)&b[0] = *(const float4*)&Bs[kk][tx * 8];
      *(float4*)&b[4] = *(const float4*)&Bs[kk][tx * 8 + 4];
#pragma unroll
      for (int i = 0; i < 8; ++i)
#pragma unroll
        for (int j = 0; j < 8; ++j) acc[i][j] = fmaf(a[i], b[j], acc[i][j]);
    }
    __syncthreads();
  }
#pragma unroll
  for (int i = 0; i < 8; ++i) {
    int m = m0 + ty * 8 + i;
    int e0 = n0 + tx * 8;
    float4 r0, r1;
    r0.x = acc[i][0] + bias[e0 + 0]; r0.y = acc[i][1] + bias[e0 + 1];
    r0.z = acc[i][2] + bias[e0 + 2]; r0.w = acc[i][3] + bias[e0 + 3];
    r1.x = acc[i][4] + bias[e0 + 4]; r1.y = acc[i][5] + bias[e0 + 5];
    r1.z = acc[i][6] + bias[e0 + 6]; r1.w = acc[i][7] + bias[e0 + 7];
    *(float4*)(out + (size_t)m * DMODEL + e0) = r0;
    *(float4*)(out + (size_t)m * DMODEL + e0 + 4) = r1;
  }
}

// Per-(b,h) column sums of V, for the all-masked fallback (uniform softmax).
__global__ __launch_bounds__(256) void vsum_kernel(const float* __restrict__ V,
                                                   float* __restrict__ vsum) {
  const int bh = blockIdx.x;
  const int tid = threadIdx.x;
  const int d = tid & 63, part = tid >> 6;  // 4 parts
  const float* Vp = V + (size_t)bh * S_LEN * HDIM;
  float s = 0.f;
  for (int k = part * 512; k < (part + 1) * 512; ++k) s += Vp[(size_t)k * HDIM + d];
  __shared__ float red[4][64];
  red[part][d] = s;
  __syncthreads();
  if (part == 0) vsum[bh * HDIM + d] = red[0][d] + red[1][d] + red[2][d] + red[3][d];
}

// Fused two-pass pruned attention. One block = one (b,h) and a 64-query tile.
// Pass 1: online (m, Z) over all K. Mask condition att1 > t  <=>  exp(l-m) > t*Z.
// Pass 2: recompute logits, keep/prune, accumulate Z2 and P*V.
__global__ __launch_bounds__(256) void attn_kernel(
    const float* __restrict__ Q, const float* __restrict__ Kg,
    const float* __restrict__ Vg, const float* __restrict__ thr,
    const float* __restrict__ vsum, float* __restrict__ values) {
  const int blk = blockIdx.x;
  const int qt = blk & 31, bh = blk >> 5;
  const int h = bh & (NH - 1), bb = bh >> 4;
  const int tid = threadIdx.x;
  const int tx = tid & 15, qy = tid >> 4;  // 16 x 16 threads

  __shared__ float Qs[64][68], Ks[64][68], Vs[64][68], Ps[64][68];
  __shared__ float m_lds[64], Z_lds[64], Z2_lds[64], tz_lds[64];

  const float* Qp = Q + ((size_t)bh * S_LEN + qt * 64) * HDIM;
  const float* Kp = Kg + (size_t)bh * S_LEN * HDIM;
  const float* Vp = Vg + (size_t)bh * S_LEN * HDIM;

  // load Q tile (64x64)
  {
    int row = tid >> 2, seg = tid & 3;
#pragma unroll
    for (int j = 0; j < 4; ++j) {
      int c = (seg + j * 4) * 4;
      *(float4*)&Qs[row][c] = *(const float4*)(Qp + (size_t)row * HDIM + c);
    }
  }
  if (tid < 64) { m_lds[tid] = -INFINITY; Z_lds[tid] = 0.f; Z2_lds[tid] = 0.f; }
  __syncthreads();

  // ---------------- pass 1: row max + denominator ----------------
  for (int t = 0; t < 32; ++t) {
    {
      int row = tid >> 2, seg = tid & 3;
#pragma unroll
      for (int j = 0; j < 4; ++j) {
        int c = (seg + j * 4) * 4;
        *(float4*)&Ks[row][c] = *(const float4*)(Kp + (size_t)(t * 64 + row) * HDIM + c);
      }
    }
    __syncthreads();
    float acc[4][4] = {};
#pragma unroll 4
    for (int dd = 0; dd < 64; dd += 4) {
      float4 qv[4], kv[4];
#pragma unroll
      for (int i = 0; i < 4; ++i) qv[i] = *(const float4*)&Qs[qy * 4 + i][dd];
#pragma unroll
      for (int j = 0; j < 4; ++j) kv[j] = *(const float4*)&Ks[tx + 16 * j][dd];
#pragma unroll
      for (int i = 0; i < 4; ++i)
#pragma unroll
        for (int j = 0; j < 4; ++j) {
          acc[i][j] = fmaf(qv[i].x, kv[j].x, acc[i][j]);
          acc[i][j] = fmaf(qv[i].y, kv[j].y, acc[i][j]);
          acc[i][j] = fmaf(qv[i].z, kv[j].z, acc[i][j]);
          acc[i][j] = fmaf(qv[i].w, kv[j].w, acc[i][j]);
        }
    }
#pragma unroll
    for (int i = 0; i < 4; ++i) {
      int q = qy * 4 + i;
      float l0 = acc[i][0] * SCALE, l1 = acc[i][1] * SCALE;
      float l2 = acc[i][2] * SCALE, l3 = acc[i][3] * SCALE;
      float tmax = fmaxf(fmaxf(l0, l1), fmaxf(l2, l3));
#pragma unroll
      for (int off = 8; off >= 1; off >>= 1)
        tmax = fmaxf(tmax, __shfl_xor(tmax, off, 16));
      float mold = m_lds[q];
      float mnew = fmaxf(mold, tmax);
      float es = expf(l0 - mnew) + expf(l1 - mnew) + expf(l2 - mnew) + expf(l3 - mnew);
#pragma unroll
      for (int off = 8; off >= 1; off >>= 1) es += __shfl_xor(es, off, 16);
      if (tx == 0) {
        m_lds[q] = mnew;
        Z_lds[q] = Z_lds[q] * expf(mold - mnew) + es;
      }
    }
    __syncthreads();
  }

  if (tid < 64) tz_lds[tid] = thr[h] * Z_lds[tid];
  __syncthreads();

  // ---------------- pass 2: masked softmax + PV ----------------
  float oacc[4][4] = {};
  for (int t = 0; t < 32; ++t) {
    {
      int row = tid >> 2, seg = tid & 3;
#pragma unroll
      for (int j = 0; j < 4; ++j) {
        int c = (seg + j * 4) * 4;
        *(float4*)&Ks[row][c] = *(const float4*)(Kp + (size_t)(t * 64 + row) * HDIM + c);
        *(float4*)&Vs[row][c] = *(const float4*)(Vp + (size_t)(t * 64 + row) * HDIM + c);
      }
    }
    __syncthreads();
    float acc[4][4] = {};
#pragma unroll 4
    for (int dd = 0; dd < 64; dd += 4) {
      float4 qv[4], kv[4];
#pragma unroll
      for (int i = 0; i < 4; ++i) qv[i] = *(const float4*)&Qs[qy * 4 + i][dd];
#pragma unroll
      for (int j = 0; j < 4; ++j) kv[j] = *(const float4*)&Ks[tx + 16 * j][dd];
#pragma unroll
      for (int i = 0; i < 4; ++i)
#pragma unroll
        for (int j = 0; j < 4; ++j) {
          acc[i][j] = fmaf(qv[i].x, kv[j].x, acc[i][j]);
          acc[i][j] = fmaf(qv[i].y, kv[j].y, acc[i][j]);
          acc[i][j] = fmaf(qv[i].z, kv[j].z, acc[i][j]);
          acc[i][j] = fmaf(qv[i].w, kv[j].w, acc[i][j]);
        }
    }
#pragma unroll
    for (int i = 0; i < 4; ++i) {
      int q = qy * 4 + i;
      float mq = m_lds[q], tzq = tz_lds[q];
      float ps = 0.f;
#pragma unroll
      for (int j = 0; j < 4; ++j) {
        float pu = expf(acc[i][j] * SCALE - mq);
        float p = (pu > tzq) ? pu : 0.f;
        Ps[q][tx + 16 * j] = p;
        ps += p;
      }
#pragma unroll
      for (int off = 8; off >= 1; off >>= 1) ps += __shfl_xor(ps, off, 16);
      if (tx == 0) Z2_lds[q] += ps;
    }
    __syncthreads();
#pragma unroll 4
    for (int k = 0; k < 64; ++k) {
      float4 vv = *(const float4*)&Vs[k][tx * 4];
#pragma unroll
      for (int i = 0; i < 4; ++i) {
        float p = Ps[qy * 4 + i][k];
        oacc[i][0] = fmaf(p, vv.x, oacc[i][0]);
        oacc[i][1] = fmaf(p, vv.y, oacc[i][1]);
        oacc[i][2] = fmaf(p, vv.z, oacc[i][2]);
        oacc[i][3] = fmaf(p, vv.w, oacc[i][3]);
      }
    }
    __syncthreads();
  }

  // ---------------- epilogue: normalize (or uniform fallback), write ----
#pragma unroll
  for (int i = 0; i < 4; ++i) {
    int q = qy * 4 + i;
    float z2 = Z2_lds[q];
    float4 o;
    if (z2 > 0.f) {
      float inv = 1.0f / z2;
      o.x = oacc[i][0] * inv; o.y = oacc[i][1] * inv;
      o.z = oacc[i][2] * inv; o.w = oacc[i][3] * inv;
    } else {
      // no entry passed the threshold: softmax over all-NEG row = uniform
      float4 vs4 = *(const float4*)(vsum + bh * HDIM + tx * 4);
      const float invS = 1.0f / (float)S_LEN;
      o.x = vs4.x * invS; o.y = vs4.y * invS; o.z = vs4.z * invS; o.w = vs4.w * invS;
    }
    size_t off = ((size_t)bb * S_LEN + qt * 64 + q) * DMODEL + h * HDIM + tx * 4;
    *(float4*)(values + off) = o;
  }
}

extern "C" void kernel_launch(void* const* d_in, const int* in_sizes, int n_in,
                              void* d_out, int out_size, void* d_ws, size_t ws_size,
                              hipStream_t stream) {
  const float* x = (const float*)d_in[0];
  const float* thresholds = (const float*)d_in[1];
  const float* qkv_w = (const float*)d_in[2];
  const float* qkv_b = (const float*)d_in[3];
  const float* o_w = (const float*)d_in[4];
  const float* o_b = (const float*)d_in[5];
  float* out = (float*)d_out;
  float* ws = (float*)d_ws;

  const size_t NBH = (size_t)BATCH * NH * S_LEN * HDIM;  // 4194304
  float* Q = ws;
  float* K = ws + NBH;
  float* V = ws + 2 * NBH;
  float* vsum = ws + 3 * NBH;                 // B*H*HD = 2048
  float* values = ws + 3 * NBH + 2048;        // B*S*D = 4194304

  dim3 g1(32, 24);
  qkv_gemm_kernel<<<g1, 256, 0, stream>>>(x, qkv_w, qkv_b, Q, K, V);
  vsum_kernel<<<BATCH * NH, 256, 0, stream>>>(V, vsum);
  attn_kernel<<<BATCH * NH * (S_LEN / 64), 256, 0, stream>>>(Q, K, V, thresholds,
                                                             vsum, values);
  dim3 g3(32, 8);
  o_gemm_kernel<<<g3, 256, 0, stream>>>(values, o_w, o_b, out);
}

// Round 2
// 1270.581 us; speedup vs baseline: 1.1718x; 1.1718x over previous
//
#include <hip/hip_runtime.h>
#include <math.h>

#define BATCH 2
#define S_LEN 2048
#define DMODEL 1024
#define NH 16
#define HDIM 64
#define SCALE 0.125f

typedef short bf16x8 __attribute__((ext_vector_type(8)));
typedef float f32x4 __attribute__((ext_vector_type(4)));
#define MFMA(a, b, c) __builtin_amdgcn_mfma_f32_16x16x32_bf16(a, b, c, 0, 0, 0)

static __device__ __forceinline__ float bf2f(unsigned short u) {
  return __uint_as_float(((unsigned int)u) << 16);
}

// round-to-nearest-even split: a ~= hi + lo, both bf16
static __device__ __forceinline__ void split_bf16(float a, unsigned short& hi,
                                                  unsigned short& lo) {
  unsigned int u = __float_as_uint(a);
  unsigned int r = (u + 0x7fffu + ((u >> 16) & 1u)) >> 16;
  hi = (unsigned short)r;
  float res = a - __uint_as_float(r << 16);
  unsigned int u2 = __float_as_uint(res);
  lo = (unsigned short)((u2 + 0x7fffu + ((u2 >> 16) & 1u)) >> 16);
}

static __device__ __forceinline__ float qredmax(float v) {
#pragma unroll
  for (int off = 8; off >= 1; off >>= 1) v = fmaxf(v, __shfl_xor(v, off, 16));
  return v;
}
static __device__ __forceinline__ float qredsum(float v) {
#pragma unroll
  for (int off = 8; off >= 1; off >>= 1) v += __shfl_xor(v, off, 16);
  return v;
}

// ---------------- SGEMM config: C[M,N] = A[M,K] * W[N,K]^T + bias ----------
#define BM 128
#define BN 128
#define BK 16

// QKV projection -> split-bf16 Q,K [bh][s][d] and transposed V [bh][d][s]
__global__ __launch_bounds__(256) void qkv_gemm_kernel(
    const float* __restrict__ x, const float* __restrict__ w,
    const float* __restrict__ bias, unsigned short* __restrict__ Qhi,
    unsigned short* __restrict__ Qlo, unsigned short* __restrict__ Khi,
    unsigned short* __restrict__ Klo, unsigned short* __restrict__ Vthi,
    unsigned short* __restrict__ Vtlo) {
  __shared__ float As[BK][BM + 8];
  __shared__ float Bs[BK][BN + 8];
  const int tid = threadIdx.x;
  const int tx = tid & 15, ty = tid >> 4;
  const int m0 = blockIdx.x * BM, n0 = blockIdx.y * BN;
  float acc[8][8] = {};
  for (int k0 = 0; k0 < DMODEL; k0 += BK) {
#pragma unroll
    for (int l = 0; l < 2; ++l) {
      int idx = tid + l * 256;
      int mm = idx >> 2, ks = (idx & 3) << 2;
      float4 v4 = *(const float4*)(x + (size_t)(m0 + mm) * DMODEL + k0 + ks);
      As[ks + 0][mm] = v4.x; As[ks + 1][mm] = v4.y;
      As[ks + 2][mm] = v4.z; As[ks + 3][mm] = v4.w;
    }
#pragma unroll
    for (int l = 0; l < 2; ++l) {
      int idx = tid + l * 256;
      int nn = idx >> 2, ks = (idx & 3) << 2;
      float4 v4 = *(const float4*)(w + (size_t)(n0 + nn) * DMODEL + k0 + ks);
      Bs[ks + 0][nn] = v4.x; Bs[ks + 1][nn] = v4.y;
      Bs[ks + 2][nn] = v4.z; Bs[ks + 3][nn] = v4.w;
    }
    __syncthreads();
#pragma unroll
    for (int kk = 0; kk < BK; ++kk) {
      float a[8], b[8];
      *(float4*)&a[0] = *(const float4*)&As[kk][ty * 8];
      *(float4*)&a[4] = *(const float4*)&As[kk][ty * 8 + 4];
      *(float4*)&b[0] = *(const float4*)&Bs[kk][tx * 8];
      *(float4*)&b[4] = *(const float4*)&Bs[kk][tx * 8 + 4];
#pragma unroll
      for (int i = 0; i < 8; ++i)
#pragma unroll
        for (int j = 0; j < 8; ++j) acc[i][j] = fmaf(a[i], b[j], acc[i][j]);
    }
    __syncthreads();
  }
#pragma unroll
  for (int i = 0; i < 8; ++i) {
    int mrow = m0 + ty * 8 + i;
    int bb = mrow >> 11, s = mrow & (S_LEN - 1);
#pragma unroll
    for (int j = 0; j < 8; ++j) {
      int e = n0 + tx * 8 + j;
      float val = acc[i][j] + bias[e];
      int h = e / 192;
      int r = e - h * 192;
      int d = r & 63;
      unsigned short hi, lo;
      split_bf16(val, hi, lo);
      int bh = bb * NH + h;
      if (r < 64) {
        int off = (bh * S_LEN + s) * HDIM + d;
        Qhi[off] = hi; Qlo[off] = lo;
      } else if (r < 128) {
        int off = (bh * S_LEN + s) * HDIM + d;
        Khi[off] = hi; Klo[off] = lo;
      } else {
        int off = (bh * HDIM + d) * S_LEN + s;
        Vthi[off] = hi; Vtlo[off] = lo;
      }
    }
  }
}

// Output projection: values[4096,1024] @ o_w[1024,1024]^T + o_b -> out
__global__ __launch_bounds__(256) void o_gemm_kernel(
    const float* __restrict__ A, const float* __restrict__ w,
    const float* __restrict__ bias, float* __restrict__ out) {
  __shared__ float As[BK][BM + 8];
  __shared__ float Bs[BK][BN + 8];
  const int tid = threadIdx.x;
  const int tx = tid & 15, ty = tid >> 4;
  const int m0 = blockIdx.x * BM, n0 = blockIdx.y * BN;
  float acc[8][8] = {};
  for (int k0 = 0; k0 < DMODEL; k0 += BK) {
#pragma unroll
    for (int l = 0; l < 2; ++l) {
      int idx = tid + l * 256;
      int mm = idx >> 2, ks = (idx & 3) << 2;
      float4 v4 = *(const float4*)(A + (size_t)(m0 + mm) * DMODEL + k0 + ks);
      As[ks + 0][mm] = v4.x; As[ks + 1][mm] = v4.y;
      As[ks + 2][mm] = v4.z; As[ks + 3][mm] = v4.w;
    }
#pragma unroll
    for (int l = 0; l < 2; ++l) {
      int idx = tid + l * 256;
      int nn = idx >> 2, ks = (idx & 3) << 2;
      float4 v4 = *(const float4*)(w + (size_t)(n0 + nn) * DMODEL + k0 + ks);
      Bs[ks + 0][nn] = v4.x; Bs[ks + 1][nn] = v4.y;
      Bs[ks + 2][nn] = v4.z; Bs[ks + 3][nn] = v4.w;
    }
    __syncthreads();
#pragma unroll
    for (int kk = 0; kk < BK; ++kk) {
      float a[8], b[8];
      *(float4*)&a[0] = *(const float4*)&As[kk][ty * 8];
      *(float4*)&a[4] = *(const float4*)&As[kk][ty * 8 + 4];
      *(float4*)&b[0] = *(const float4*)&Bs[kk][tx * 8];
      *(float4*)&b[4] = *(const float4*)&Bs[kk][tx * 8 + 4];
#pragma unroll
      for (int i = 0; i < 8; ++i)
#pragma unroll
        for (int j = 0; j < 8; ++j) acc[i][j] = fmaf(a[i], b[j], acc[i][j]);
    }
    __syncthreads();
  }
#pragma unroll
  for (int i = 0; i < 8; ++i) {
    int mrow = m0 + ty * 8 + i;
    int e0 = n0 + tx * 8;
    float4 r0, r1;
    r0.x = acc[i][0] + bias[e0 + 0]; r0.y = acc[i][1] + bias[e0 + 1];
    r0.z = acc[i][2] + bias[e0 + 2]; r0.w = acc[i][3] + bias[e0 + 3];
    r1.x = acc[i][4] + bias[e0 + 4]; r1.y = acc[i][5] + bias[e0 + 5];
    r1.z = acc[i][6] + bias[e0 + 6]; r1.w = acc[i][7] + bias[e0 + 7];
    *(float4*)(out + (size_t)mrow * DMODEL + e0) = r0;
    *(float4*)(out + (size_t)mrow * DMODEL + e0 + 4) = r1;
  }
}

// Per-(b,h) column sums of V (from transposed hi/lo), for all-pruned fallback.
__global__ __launch_bounds__(256) void vsum_kernel(
    const unsigned short* __restrict__ Vthi,
    const unsigned short* __restrict__ Vtlo, float* __restrict__ vsum) {
  const int bh = blockIdx.x;
  const int tid = threadIdx.x;
  const int d = tid >> 2, part = tid & 3;
  int base = (bh * HDIM + d) * S_LEN + part * 512;
  float s = 0.f;
  for (int k = 0; k < 512; ++k) s += bf2f(Vthi[base + k]) + bf2f(Vtlo[base + k]);
  __shared__ float red[64][4];
  red[d][part] = s;
  __syncthreads();
  if (part == 0)
    vsum[bh * HDIM + d] = red[d][0] + red[d][1] + red[d][2] + red[d][3];
}

// Fused two-pass pruned attention, split-bf16 MFMA.
// Block = (b,h, 64-query tile); 4 waves; wave owns 16 q rows.
__global__ __launch_bounds__(256) void attn_mfma_kernel(
    const unsigned short* __restrict__ Qhi, const unsigned short* __restrict__ Qlo,
    const unsigned short* __restrict__ Khi, const unsigned short* __restrict__ Klo,
    const unsigned short* __restrict__ Vthi, const unsigned short* __restrict__ Vtlo,
    const float* __restrict__ thr, const float* __restrict__ vsum,
    float* __restrict__ values) {
  const int blk = blockIdx.x;
  const int qt = blk & 31, bh = blk >> 5;
  const int h = bh & (NH - 1), bb = bh >> 4;
  const int tid = threadIdx.x;
  const int w = tid >> 6, lane = tid & 63;
  const int m = lane & 15, quad = lane >> 4;

  __shared__ unsigned short Phi_s[4][16][64];
  __shared__ unsigned short Plo_s[4][16][64];

  // persistent Q fragments (A-operand: A[m=lane&15][k=quad*8+j])
  const int qoff = (bh * S_LEN + qt * 64 + w * 16 + m) * HDIM + quad * 8;
  const bf16x8 aQh0 = *(const bf16x8*)(Qhi + qoff);
  const bf16x8 aQh1 = *(const bf16x8*)(Qhi + qoff + 32);
  const bf16x8 aQl0 = *(const bf16x8*)(Qlo + qoff);
  const bf16x8 aQl1 = *(const bf16x8*)(Qlo + qoff + 32);

  const int kbase = bh * S_LEN * HDIM;
  const float th = thr[h];

  float mr[4], Zr[4], Z2r[4], tzr[4];
#pragma unroll
  for (int r = 0; r < 4; ++r) { mr[r] = -INFINITY; Zr[r] = 0.f; Z2r[r] = 0.f; }

  const f32x4 vzero = {0.f, 0.f, 0.f, 0.f};

  // ---------------- pass 1: row max + denominator (no LDS, no barriers) ----
  for (int t = 0; t < 32; ++t) {
    const unsigned short* kc = Khi + kbase + t * 64 * HDIM;
    const unsigned short* kcl = Klo + kbase + t * 64 * HDIM;
    f32x4 acc[4];
#pragma unroll
    for (int nt = 0; nt < 4; ++nt) acc[nt] = vzero;
#pragma unroll
    for (int nt = 0; nt < 4; ++nt) {
      int ko = (nt * 16 + m) * HDIM + quad * 8;
      bf16x8 kh0 = *(const bf16x8*)(kc + ko);
      bf16x8 kh1 = *(const bf16x8*)(kc + ko + 32);
      bf16x8 kl0 = *(const bf16x8*)(kcl + ko);
      bf16x8 kl1 = *(const bf16x8*)(kcl + ko + 32);
      acc[nt] = MFMA(aQh0, kh0, acc[nt]);
      acc[nt] = MFMA(aQh1, kh1, acc[nt]);
      acc[nt] = MFMA(aQh0, kl0, acc[nt]);
      acc[nt] = MFMA(aQh1, kl1, acc[nt]);
      acc[nt] = MFMA(aQl0, kh0, acc[nt]);
      acc[nt] = MFMA(aQl1, kh1, acc[nt]);
      acc[nt] = MFMA(aQl0, kl0, acc[nt]);
      acc[nt] = MFMA(aQl1, kl1, acc[nt]);
    }
#pragma unroll
    for (int r = 0; r < 4; ++r) {
      float l0 = acc[0][r] * SCALE, l1 = acc[1][r] * SCALE;
      float l2 = acc[2][r] * SCALE, l3 = acc[3][r] * SCALE;
      float tmax = qredmax(fmaxf(fmaxf(l0, l1), fmaxf(l2, l3)));
      float mnew = fmaxf(mr[r], tmax);
      float es = expf(l0 - mnew) + expf(l1 - mnew) + expf(l2 - mnew) + expf(l3 - mnew);
      es = qredsum(es);
      Zr[r] = Zr[r] * expf(mr[r] - mnew) + es;
      mr[r] = mnew;
    }
  }
#pragma unroll
  for (int r = 0; r < 4; ++r) tzr[r] = th * Zr[r];

  // ---------------- pass 2: masked softmax + PV ----------------
  f32x4 oacc[4];
#pragma unroll
  for (int nt = 0; nt < 4; ++nt) oacc[nt] = vzero;

  for (int t = 0; t < 32; ++t) {
    const unsigned short* kc = Khi + kbase + t * 64 * HDIM;
    const unsigned short* kcl = Klo + kbase + t * 64 * HDIM;
    f32x4 acc[4];
#pragma unroll
    for (int nt = 0; nt < 4; ++nt) acc[nt] = vzero;
#pragma unroll
    for (int nt = 0; nt < 4; ++nt) {
      int ko = (nt * 16 + m) * HDIM + quad * 8;
      bf16x8 kh0 = *(const bf16x8*)(kc + ko);
      bf16x8 kh1 = *(const bf16x8*)(kc + ko + 32);
      bf16x8 kl0 = *(const bf16x8*)(kcl + ko);
      bf16x8 kl1 = *(const bf16x8*)(kcl + ko + 32);
      acc[nt] = MFMA(aQh0, kh0, acc[nt]);
      acc[nt] = MFMA(aQh1, kh1, acc[nt]);
      acc[nt] = MFMA(aQh0, kl0, acc[nt]);
      acc[nt] = MFMA(aQh1, kl1, acc[nt]);
      acc[nt] = MFMA(aQl0, kh0, acc[nt]);
      acc[nt] = MFMA(aQl1, kh1, acc[nt]);
      acc[nt] = MFMA(aQl0, kl0, acc[nt]);
      acc[nt] = MFMA(aQl1, kl1, acc[nt]);
    }
    // prune + stage P (hi/lo) into xor-swizzled per-wave LDS
#pragma unroll
    for (int r = 0; r < 4; ++r) {
      int row = quad * 4 + r;
      float psum = 0.f;
#pragma unroll
      for (int nt = 0; nt < 4; ++nt) {
        float pu = expf(acc[nt][r] * SCALE - mr[r]);
        float p = (pu > tzr[r]) ? pu : 0.f;
        psum += p;
        int col = nt * 16 + m;
        int cs = (((col >> 3) ^ (row & 7)) << 3) | (col & 7);
        unsigned short phi_u, plo_u;
        split_bf16(p, phi_u, plo_u);
        Phi_s[w][row][cs] = phi_u;
        Plo_s[w][row][cs] = plo_u;
      }
      Z2r[r] += qredsum(psum);
    }
    // P A-fragments from swizzled LDS (conflict-free b128)
    int b0 = ((quad) ^ (m & 7)) * 8;
    int b1 = ((4 + quad) ^ (m & 7)) * 8;
    bf16x8 aPh0 = *(const bf16x8*)&Phi_s[w][m][b0];
    bf16x8 aPh1 = *(const bf16x8*)&Phi_s[w][m][b1];
    bf16x8 aPl0 = *(const bf16x8*)&Plo_s[w][m][b0];
    bf16x8 aPl1 = *(const bf16x8*)&Plo_s[w][m][b1];
    // PV: B-operand from transposed V (B[n=d][k=key])
#pragma unroll
    for (int nt = 0; nt < 4; ++nt) {
      int vo = (bh * HDIM + nt * 16 + m) * S_LEN + t * 64 + quad * 8;
      bf16x8 vh0 = *(const bf16x8*)(Vthi + vo);
      bf16x8 vh1 = *(const bf16x8*)(Vthi + vo + 32);
      bf16x8 vl0 = *(const bf16x8*)(Vtlo + vo);
      bf16x8 vl1 = *(const bf16x8*)(Vtlo + vo + 32);
      oacc[nt] = MFMA(aPh0, vh0, oacc[nt]);
      oacc[nt] = MFMA(aPh1, vh1, oacc[nt]);
      oacc[nt] = MFMA(aPh0, vl0, oacc[nt]);
      oacc[nt] = MFMA(aPh1, vl1, oacc[nt]);
      oacc[nt] = MFMA(aPl0, vh0, oacc[nt]);
      oacc[nt] = MFMA(aPl1, vh1, oacc[nt]);
    }
  }

  // ---------------- epilogue: normalize (or uniform fallback), write -------
#pragma unroll
  for (int r = 0; r < 4; ++r) {
    float z2 = Z2r[r];
    float invz = (z2 > 0.f) ? (1.f / z2) : 0.f;
    int srow = qt * 64 + w * 16 + quad * 4 + r;
#pragma unroll
    for (int nt = 0; nt < 4; ++nt) {
      float vs = vsum[bh * HDIM + nt * 16 + m];
      float o = (z2 > 0.f) ? (oacc[nt][r] * invz) : (vs * (1.0f / S_LEN));
      values[(bb * S_LEN + srow) * DMODEL + h * HDIM + nt * 16 + m] = o;
    }
  }
}

extern "C" void kernel_launch(void* const* d_in, const int* in_sizes, int n_in,
                              void* d_out, int out_size, void* d_ws, size_t ws_size,
                              hipStream_t stream) {
  const float* x = (const float*)d_in[0];
  const float* thresholds = (const float*)d_in[1];
  const float* qkv_w = (const float*)d_in[2];
  const float* qkv_b = (const float*)d_in[3];
  const float* o_w = (const float*)d_in[4];
  const float* o_b = (const float*)d_in[5];
  float* out = (float*)d_out;

  const size_t NBH = (size_t)BATCH * NH * S_LEN * HDIM;  // 4194304
  unsigned short* Qhi = (unsigned short*)d_ws;
  unsigned short* Qlo = Qhi + NBH;
  unsigned short* Khi = Qhi + 2 * NBH;
  unsigned short* Klo = Qhi + 3 * NBH;
  unsigned short* Vthi = Qhi + 4 * NBH;
  unsigned short* Vtlo = Qhi + 5 * NBH;
  float* vsum = (float*)(Qhi + 6 * NBH);       // B*H*HD = 2048
  float* values = vsum + 2048;                 // B*S*D  = 4194304

  dim3 g1(32, 24);
  qkv_gemm_kernel<<<g1, 256, 0, stream>>>(x, qkv_w, qkv_b, Qhi, Qlo, Khi, Klo,
                                          Vthi, Vtlo);
  vsum_kernel<<<BATCH * NH, 256, 0, stream>>>(Vthi, Vtlo, vsum);
  attn_mfma_kernel<<<BATCH * NH * (S_LEN / 64), 256, 0, stream>>>(
      Qhi, Qlo, Khi, Klo, Vthi, Vtlo, thresholds, vsum, values);
  dim3 g3(32, 8);
  o_gemm_kernel<<<g3, 256, 0, stream>>>(values, o_w, o_b, out);
}

// Round 3
// 899.697 us; speedup vs baseline: 1.6548x; 1.4122x over previous
//
#include <hip/hip_runtime.h>
#include <math.h>

#define BATCH 2
#define S_LEN 2048
#define DMODEL 1024
#define NH 16
#define HDIM 64
#define SCALE 0.125f

typedef short bf16x8 __attribute__((ext_vector_type(8)));
typedef float f32x4 __attribute__((ext_vector_type(4)));
#define MFMA(a, b, c) __builtin_amdgcn_mfma_f32_16x16x32_bf16(a, b, c, 0, 0, 0)

static __device__ __forceinline__ float bf2f(unsigned short u) {
  return __uint_as_float(((unsigned int)u) << 16);
}

// round-to-nearest-even split: a ~= hi + lo, both bf16
static __device__ __forceinline__ void split_bf16(float a, unsigned short& hi,
                                                  unsigned short& lo) {
  unsigned int u = __float_as_uint(a);
  unsigned int r = (u + 0x7fffu + ((u >> 16) & 1u)) >> 16;
  hi = (unsigned short)r;
  float res = a - __uint_as_float(r << 16);
  unsigned int u2 = __float_as_uint(res);
  lo = (unsigned short)((u2 + 0x7fffu + ((u2 >> 16) & 1u)) >> 16);
}

static __device__ __forceinline__ float qredmax(float v) {
#pragma unroll
  for (int off = 8; off >= 1; off >>= 1) v = fmaxf(v, __shfl_xor(v, off, 16));
  return v;
}
static __device__ __forceinline__ float qredsum(float v) {
#pragma unroll
  for (int off = 8; off >= 1; off >>= 1) v += __shfl_xor(v, off, 16);
  return v;
}

// async global->LDS, 16B per lane; LDS dest = wave-uniform base + lane*16
static __device__ __forceinline__ void async_ld16(unsigned short* lds,
                                                  const unsigned short* g) {
  __builtin_amdgcn_global_load_lds(
      (const __attribute__((address_space(1))) void*)(const void*)g,
      (__attribute__((address_space(3))) void*)(void*)lds, 16, 0, 0);
}

// ---------------- SGEMM config: C[M,N] = A[M,K] * W[N,K]^T + bias ----------
#define BM 128
#define BN 128
#define BK 16

// QKV projection -> split-bf16 Q,K [bh][s][d] and transposed V [bh][d][s]
__global__ __launch_bounds__(256) void qkv_gemm_kernel(
    const float* __restrict__ x, const float* __restrict__ w,
    const float* __restrict__ bias, unsigned short* __restrict__ Qhi,
    unsigned short* __restrict__ Qlo, unsigned short* __restrict__ Khi,
    unsigned short* __restrict__ Klo, unsigned short* __restrict__ Vthi,
    unsigned short* __restrict__ Vtlo) {
  __shared__ float As[BK][BM + 8];
  __shared__ float Bs[BK][BN + 8];
  const int tid = threadIdx.x;
  const int tx = tid & 15, ty = tid >> 4;
  const int m0 = blockIdx.x * BM, n0 = blockIdx.y * BN;
  float acc[8][8] = {};
  for (int k0 = 0; k0 < DMODEL; k0 += BK) {
#pragma unroll
    for (int l = 0; l < 2; ++l) {
      int idx = tid + l * 256;
      int mm = idx >> 2, ks = (idx & 3) << 2;
      float4 v4 = *(const float4*)(x + (size_t)(m0 + mm) * DMODEL + k0 + ks);
      As[ks + 0][mm] = v4.x; As[ks + 1][mm] = v4.y;
      As[ks + 2][mm] = v4.z; As[ks + 3][mm] = v4.w;
    }
#pragma unroll
    for (int l = 0; l < 2; ++l) {
      int idx = tid + l * 256;
      int nn = idx >> 2, ks = (idx & 3) << 2;
      float4 v4 = *(const float4*)(w + (size_t)(n0 + nn) * DMODEL + k0 + ks);
      Bs[ks + 0][nn] = v4.x; Bs[ks + 1][nn] = v4.y;
      Bs[ks + 2][nn] = v4.z; Bs[ks + 3][nn] = v4.w;
    }
    __syncthreads();
#pragma unroll
    for (int kk = 0; kk < BK; ++kk) {
      float a[8], b[8];
      *(float4*)&a[0] = *(const float4*)&As[kk][ty * 8];
      *(float4*)&a[4] = *(const float4*)&As[kk][ty * 8 + 4];
      *(float4*)&b[0] = *(const float4*)&Bs[kk][tx * 8];
      *(float4*)&b[4] = *(const float4*)&Bs[kk][tx * 8 + 4];
#pragma unroll
      for (int i = 0; i < 8; ++i)
#pragma unroll
        for (int j = 0; j < 8; ++j) acc[i][j] = fmaf(a[i], b[j], acc[i][j]);
    }
    __syncthreads();
  }
#pragma unroll
  for (int i = 0; i < 8; ++i) {
    int mrow = m0 + ty * 8 + i;
    int bb = mrow >> 11, s = mrow & (S_LEN - 1);
#pragma unroll
    for (int j = 0; j < 8; ++j) {
      int e = n0 + tx * 8 + j;
      float val = acc[i][j] + bias[e];
      int h = e / 192;
      int r = e - h * 192;
      int d = r & 63;
      unsigned short hi, lo;
      split_bf16(val, hi, lo);
      int bh = bb * NH + h;
      if (r < 64) {
        int off = (bh * S_LEN + s) * HDIM + d;
        Qhi[off] = hi; Qlo[off] = lo;
      } else if (r < 128) {
        int off = (bh * S_LEN + s) * HDIM + d;
        Khi[off] = hi; Klo[off] = lo;
      } else {
        int off = (bh * HDIM + d) * S_LEN + s;
        Vthi[off] = hi; Vtlo[off] = lo;
      }
    }
  }
}

// Output projection: values[4096,1024] @ o_w[1024,1024]^T + o_b -> out
__global__ __launch_bounds__(256) void o_gemm_kernel(
    const float* __restrict__ A, const float* __restrict__ w,
    const float* __restrict__ bias, float* __restrict__ out) {
  __shared__ float As[BK][BM + 8];
  __shared__ float Bs[BK][BN + 8];
  const int tid = threadIdx.x;
  const int tx = tid & 15, ty = tid >> 4;
  const int m0 = blockIdx.x * BM, n0 = blockIdx.y * BN;
  float acc[8][8] = {};
  for (int k0 = 0; k0 < DMODEL; k0 += BK) {
#pragma unroll
    for (int l = 0; l < 2; ++l) {
      int idx = tid + l * 256;
      int mm = idx >> 2, ks = (idx & 3) << 2;
      float4 v4 = *(const float4*)(A + (size_t)(m0 + mm) * DMODEL + k0 + ks);
      As[ks + 0][mm] = v4.x; As[ks + 1][mm] = v4.y;
      As[ks + 2][mm] = v4.z; As[ks + 3][mm] = v4.w;
    }
#pragma unroll
    for (int l = 0; l < 2; ++l) {
      int idx = tid + l * 256;
      int nn = idx >> 2, ks = (idx & 3) << 2;
      float4 v4 = *(const float4*)(w + (size_t)(n0 + nn) * DMODEL + k0 + ks);
      Bs[ks + 0][nn] = v4.x; Bs[ks + 1][nn] = v4.y;
      Bs[ks + 2][nn] = v4.z; Bs[ks + 3][nn] = v4.w;
    }
    __syncthreads();
#pragma unroll
    for (int kk = 0; kk < BK; ++kk) {
      float a[8], b[8];
      *(float4*)&a[0] = *(const float4*)&As[kk][ty * 8];
      *(float4*)&a[4] = *(const float4*)&As[kk][ty * 8 + 4];
      *(float4*)&b[0] = *(const float4*)&Bs[kk][tx * 8];
      *(float4*)&b[4] = *(const float4*)&Bs[kk][tx * 8 + 4];
#pragma unroll
      for (int i = 0; i < 8; ++i)
#pragma unroll
        for (int j = 0; j < 8; ++j) acc[i][j] = fmaf(a[i], b[j], acc[i][j]);
    }
    __syncthreads();
  }
#pragma unroll
  for (int i = 0; i < 8; ++i) {
    int mrow = m0 + ty * 8 + i;
    int e0 = n0 + tx * 8;
    float4 r0, r1;
    r0.x = acc[i][0] + bias[e0 + 0]; r0.y = acc[i][1] + bias[e0 + 1];
    r0.z = acc[i][2] + bias[e0 + 2]; r0.w = acc[i][3] + bias[e0 + 3];
    r1.x = acc[i][4] + bias[e0 + 4]; r1.y = acc[i][5] + bias[e0 + 5];
    r1.z = acc[i][6] + bias[e0 + 6]; r1.w = acc[i][7] + bias[e0 + 7];
    *(float4*)(out + (size_t)mrow * DMODEL + e0) = r0;
    *(float4*)(out + (size_t)mrow * DMODEL + e0 + 4) = r1;
  }
}

// Per-(b,h) column sums of V (from transposed hi/lo), for all-pruned fallback.
__global__ __launch_bounds__(256) void vsum_kernel(
    const unsigned short* __restrict__ Vthi,
    const unsigned short* __restrict__ Vtlo, float* __restrict__ vsum) {
  const int bh = blockIdx.x;
  const int tid = threadIdx.x;
  const int d = tid >> 2, part = tid & 3;
  int base = (bh * HDIM + d) * S_LEN + part * 512;
  float s = 0.f;
  for (int k = 0; k < 512; ++k) s += bf2f(Vthi[base + k]) + bf2f(Vtlo[base + k]);
  __shared__ float red[64][4];
  red[d][part] = s;
  __syncthreads();
  if (part == 0)
    vsum[bh * HDIM + d] = red[d][0] + red[d][1] + red[d][2] + red[d][3];
}

// Fused two-pass pruned attention, split-bf16 MFMA, LDS-staged K/V.
// Block = (b,h, 64-query tile); 4 waves; wave owns 16 q rows.
__global__ __launch_bounds__(256) void attn_mfma_kernel(
    const unsigned short* __restrict__ Qhi, const unsigned short* __restrict__ Qlo,
    const unsigned short* __restrict__ Khi, const unsigned short* __restrict__ Klo,
    const unsigned short* __restrict__ Vthi, const unsigned short* __restrict__ Vtlo,
    const float* __restrict__ thr, const float* __restrict__ vsum,
    float* __restrict__ values) {
  const int blk = blockIdx.x;
  const int qt = blk & 31, bh = blk >> 5;
  const int h = bh & (NH - 1), bb = bh >> 4;
  const int tid = threadIdx.x;
  const int w = tid >> 6, lane = tid & 63;
  const int m = lane & 15, quad = lane >> 4;
  const int rsub = lane >> 3;                    // 0..7: row within 8-row chunk
  const int bsw = (lane & 7) ^ rsub;             // swizzled 16B-block index

  // 64KB total LDS: K double-buffered, V single, P hi/lo staging
  __shared__ __align__(16) unsigned short Kh_s[2][4096];
  __shared__ __align__(16) unsigned short Kl_s[2][4096];
  __shared__ __align__(16) unsigned short Vh_s[4096];
  __shared__ __align__(16) unsigned short Vl_s[4096];
  __shared__ __align__(16) unsigned short Phi_s[4][16][64];
  __shared__ __align__(16) unsigned short Plo_s[4][16][64];

  // persistent Q fragments (A-operand: A[m=lane&15][k=quad*8+j])
  const int qoff = (bh * S_LEN + qt * 64 + w * 16 + m) * HDIM + quad * 8;
  const bf16x8 aQh0 = *(const bf16x8*)(Qhi + qoff);
  const bf16x8 aQh1 = *(const bf16x8*)(Qhi + qoff + 32);
  const bf16x8 aQl0 = *(const bf16x8*)(Qlo + qoff);
  const bf16x8 aQl1 = *(const bf16x8*)(Qlo + qoff + 32);

  const unsigned short* KhT = Khi + bh * S_LEN * HDIM;
  const unsigned short* KlT = Klo + bh * S_LEN * HDIM;
  const unsigned short* VhT = Vthi + bh * HDIM * S_LEN;
  const unsigned short* VlT = Vtlo + bh * HDIM * S_LEN;
  const float th = thr[h];

  // swizzled read offsets (within a 64-short row; depends only on lane)
  const int s0 = (quad ^ (m & 7)) * 8;
  const int s1 = ((4 + quad) ^ (m & 7)) * 8;

  float mr[4], Zr[4], Z2r[4], tzr[4];
#pragma unroll
  for (int r = 0; r < 4; ++r) { mr[r] = -INFINITY; Zr[r] = 0.f; Z2r[r] = 0.f; }

  const f32x4 vzero = {0.f, 0.f, 0.f, 0.f};

  // stage helpers: each wave stages chunks {2w, 2w+1} of each 8KB tile
#define STAGE_K(bufi, t)                                                     \
  {                                                                          \
    const unsigned short* gh = KhT + (t) * 64 * 64;                          \
    const unsigned short* gl = KlT + (t) * 64 * 64;                          \
    _Pragma("unroll") for (int i = 0; i < 2; ++i) {                          \
      int c = w * 2 + i;                                                     \
      int row = c * 8 + rsub;                                                \
      async_ld16(&Kh_s[bufi][c * 512], gh + row * 64 + bsw * 8);             \
      async_ld16(&Kl_s[bufi][c * 512], gl + row * 64 + bsw * 8);             \
    }                                                                        \
  }
#define STAGE_V(t)                                                           \
  {                                                                          \
    _Pragma("unroll") for (int i = 0; i < 2; ++i) {                          \
      int c = w * 2 + i;                                                     \
      int row = c * 8 + rsub;                                                \
      async_ld16(&Vh_s[c * 512], VhT + row * 2048 + (t) * 64 + bsw * 8);     \
      async_ld16(&Vl_s[c * 512], VlT + row * 2048 + (t) * 64 + bsw * 8);     \
    }                                                                        \
  }

  // ---------------- pass 1: row max + denominator ----------------
  STAGE_K(0, 0);
  __syncthreads();
  for (int t = 0; t < 32; ++t) {
    const int cur = t & 1;
    if (t < 31) STAGE_K(cur ^ 1, t + 1);
    f32x4 acc[4];
#pragma unroll
    for (int nt = 0; nt < 4; ++nt) acc[nt] = vzero;
#pragma unroll
    for (int nt = 0; nt < 4; ++nt) {
      const int ro = (nt * 16 + m) * 64;
      bf16x8 kh0 = *(const bf16x8*)&Kh_s[cur][ro + s0];
      bf16x8 kh1 = *(const bf16x8*)&Kh_s[cur][ro + s1];
      bf16x8 kl0 = *(const bf16x8*)&Kl_s[cur][ro + s0];
      bf16x8 kl1 = *(const bf16x8*)&Kl_s[cur][ro + s1];
      acc[nt] = MFMA(aQh0, kh0, acc[nt]);
      acc[nt] = MFMA(aQh1, kh1, acc[nt]);
      acc[nt] = MFMA(aQh0, kl0, acc[nt]);
      acc[nt] = MFMA(aQh1, kl1, acc[nt]);
      acc[nt] = MFMA(aQl0, kh0, acc[nt]);
      acc[nt] = MFMA(aQl1, kh1, acc[nt]);
      acc[nt] = MFMA(aQl0, kl0, acc[nt]);
      acc[nt] = MFMA(aQl1, kl1, acc[nt]);
    }
#pragma unroll
    for (int r = 0; r < 4; ++r) {
      float l0 = acc[0][r] * SCALE, l1 = acc[1][r] * SCALE;
      float l2 = acc[2][r] * SCALE, l3 = acc[3][r] * SCALE;
      float tmax = qredmax(fmaxf(fmaxf(l0, l1), fmaxf(l2, l3)));
      float mnew = fmaxf(mr[r], tmax);
      float es = expf(l0 - mnew) + expf(l1 - mnew) + expf(l2 - mnew) + expf(l3 - mnew);
      es = qredsum(es);
      Zr[r] = Zr[r] * expf(mr[r] - mnew) + es;
      mr[r] = mnew;
    }
    __syncthreads();
  }
#pragma unroll
  for (int r = 0; r < 4; ++r) tzr[r] = th * Zr[r];

  // ---------------- pass 2: masked softmax + PV ----------------
  f32x4 oacc[4];
#pragma unroll
  for (int nt = 0; nt < 4; ++nt) oacc[nt] = vzero;

  STAGE_K(0, 0);
  __syncthreads();
  for (int t = 0; t < 32; ++t) {
    const int cur = t & 1;
    STAGE_V(t);
    if (t < 31) STAGE_K(cur ^ 1, t + 1);
    f32x4 acc[4];
#pragma unroll
    for (int nt = 0; nt < 4; ++nt) acc[nt] = vzero;
#pragma unroll
    for (int nt = 0; nt < 4; ++nt) {
      const int ro = (nt * 16 + m) * 64;
      bf16x8 kh0 = *(const bf16x8*)&Kh_s[cur][ro + s0];
      bf16x8 kh1 = *(const bf16x8*)&Kh_s[cur][ro + s1];
      bf16x8 kl0 = *(const bf16x8*)&Kl_s[cur][ro + s0];
      bf16x8 kl1 = *(const bf16x8*)&Kl_s[cur][ro + s1];
      acc[nt] = MFMA(aQh0, kh0, acc[nt]);
      acc[nt] = MFMA(aQh1, kh1, acc[nt]);
      acc[nt] = MFMA(aQh0, kl0, acc[nt]);
      acc[nt] = MFMA(aQh1, kl1, acc[nt]);
      acc[nt] = MFMA(aQl0, kh0, acc[nt]);
      acc[nt] = MFMA(aQl1, kh1, acc[nt]);
      acc[nt] = MFMA(aQl0, kl0, acc[nt]);
      acc[nt] = MFMA(aQl1, kl1, acc[nt]);
    }
    // prune + stage P (hi/lo) into xor-swizzled per-wave LDS
#pragma unroll
    for (int r = 0; r < 4; ++r) {
      int row = quad * 4 + r;
      float psum = 0.f;
#pragma unroll
      for (int nt = 0; nt < 4; ++nt) {
        float pu = expf(acc[nt][r] * SCALE - mr[r]);
        float p = (pu > tzr[r]) ? pu : 0.f;
        psum += p;
        int col = nt * 16 + m;
        int cs = (((col >> 3) ^ (row & 7)) << 3) | (col & 7);
        unsigned short phi_u, plo_u;
        split_bf16(p, phi_u, plo_u);
        Phi_s[w][row][cs] = phi_u;
        Plo_s[w][row][cs] = plo_u;
      }
      Z2r[r] += qredsum(psum);
    }
    __syncthreads();  // V(t) (and K(t+1)) staged; P visible (per-wave anyway)
    // P A-fragments from swizzled LDS (conflict-free b128)
    int b0 = ((quad) ^ (m & 7)) * 8;
    int b1 = ((4 + quad) ^ (m & 7)) * 8;
    bf16x8 aPh0 = *(const bf16x8*)&Phi_s[w][m][b0];
    bf16x8 aPh1 = *(const bf16x8*)&Phi_s[w][m][b1];
    bf16x8 aPl0 = *(const bf16x8*)&Plo_s[w][m][b0];
    bf16x8 aPl1 = *(const bf16x8*)&Plo_s[w][m][b1];
    // PV: B-operand from LDS-staged transposed V (B[n=d][k=key])
#pragma unroll
    for (int nt = 0; nt < 4; ++nt) {
      const int ro = (nt * 16 + m) * 64;
      bf16x8 vh0 = *(const bf16x8*)&Vh_s[ro + s0];
      bf16x8 vh1 = *(const bf16x8*)&Vh_s[ro + s1];
      bf16x8 vl0 = *(const bf16x8*)&Vl_s[ro + s0];
      bf16x8 vl1 = *(const bf16x8*)&Vl_s[ro + s1];
      oacc[nt] = MFMA(aPh0, vh0, oacc[nt]);
      oacc[nt] = MFMA(aPh1, vh1, oacc[nt]);
      oacc[nt] = MFMA(aPh0, vl0, oacc[nt]);
      oacc[nt] = MFMA(aPh1, vl1, oacc[nt]);
      oacc[nt] = MFMA(aPl0, vh0, oacc[nt]);
      oacc[nt] = MFMA(aPl1, vh1, oacc[nt]);
    }
    __syncthreads();  // all waves done with V buf / K[cur] before restage
  }

  // ---------------- epilogue: normalize (or uniform fallback), write -------
#pragma unroll
  for (int r = 0; r < 4; ++r) {
    float z2 = Z2r[r];
    float invz = (z2 > 0.f) ? (1.f / z2) : 0.f;
    int srow = qt * 64 + w * 16 + quad * 4 + r;
#pragma unroll
    for (int nt = 0; nt < 4; ++nt) {
      float vs = vsum[bh * HDIM + nt * 16 + m];
      float o = (z2 > 0.f) ? (oacc[nt][r] * invz) : (vs * (1.0f / S_LEN));
      values[(bb * S_LEN + srow) * DMODEL + h * HDIM + nt * 16 + m] = o;
    }
  }
}

extern "C" void kernel_launch(void* const* d_in, const int* in_sizes, int n_in,
                              void* d_out, int out_size, void* d_ws, size_t ws_size,
                              hipStream_t stream) {
  const float* x = (const float*)d_in[0];
  const float* thresholds = (const float*)d_in[1];
  const float* qkv_w = (const float*)d_in[2];
  const float* qkv_b = (const float*)d_in[3];
  const float* o_w = (const float*)d_in[4];
  const float* o_b = (const float*)d_in[5];
  float* out = (float*)d_out;

  const size_t NBH = (size_t)BATCH * NH * S_LEN * HDIM;  // 4194304
  unsigned short* Qhi = (unsigned short*)d_ws;
  unsigned short* Qlo = Qhi + NBH;
  unsigned short* Khi = Qhi + 2 * NBH;
  unsigned short* Klo = Qhi + 3 * NBH;
  unsigned short* Vthi = Qhi + 4 * NBH;
  unsigned short* Vtlo = Qhi + 5 * NBH;
  float* vsum = (float*)(Qhi + 6 * NBH);       // B*H*HD = 2048
  float* values = vsum + 2048;                 // B*S*D  = 4194304

  dim3 g1(32, 24);
  qkv_gemm_kernel<<<g1, 256, 0, stream>>>(x, qkv_w, qkv_b, Qhi, Qlo, Khi, Klo,
                                          Vthi, Vtlo);
  vsum_kernel<<<BATCH * NH, 256, 0, stream>>>(Vthi, Vtlo, vsum);
  attn_mfma_kernel<<<BATCH * NH * (S_LEN / 64), 256, 0, stream>>>(
      Qhi, Qlo, Khi, Klo, Vthi, Vtlo, thresholds, vsum, values);
  dim3 g3(32, 8);
  o_gemm_kernel<<<g3, 256, 0, stream>>>(values, o_w, o_b, out);
}

// Round 5
// 548.668 us; speedup vs baseline: 2.7135x; 1.6398x over previous
//
#include <hip/hip_runtime.h>
#include <math.h>

#define BATCH 2
#define S_LEN 2048
#define DMODEL 1024
#define NH 16
#define HDIM 64
#define SCALE 0.125f

typedef short bf16x8 __attribute__((ext_vector_type(8)));
typedef float f32x4 __attribute__((ext_vector_type(4)));
typedef unsigned short u16;
typedef unsigned short u16x4 __attribute__((ext_vector_type(4)));
#define MFMA(a, b, c) __builtin_amdgcn_mfma_f32_16x16x32_bf16(a, b, c, 0, 0, 0)

static __device__ __forceinline__ float bf2f(u16 u) {
  return __uint_as_float(((unsigned int)u) << 16);
}

// round-to-nearest-even split: a ~= hi + lo, both bf16
static __device__ __forceinline__ void split_bf16(float a, u16& hi, u16& lo) {
  unsigned int u = __float_as_uint(a);
  unsigned int r = (u + 0x7fffu + ((u >> 16) & 1u)) >> 16;
  hi = (u16)r;
  float res = a - __uint_as_float(r << 16);
  unsigned int u2 = __float_as_uint(res);
  lo = (u16)((u2 + 0x7fffu + ((u2 >> 16) & 1u)) >> 16);
}

static __device__ __forceinline__ float qredmax(float v) {
#pragma unroll
  for (int off = 8; off >= 1; off >>= 1) v = fmaxf(v, __shfl_xor(v, off, 16));
  return v;
}
static __device__ __forceinline__ float qredsum(float v) {
#pragma unroll
  for (int off = 8; off >= 1; off >>= 1) v += __shfl_xor(v, off, 16);
  return v;
}

// async global->LDS, 16B per lane; LDS dest = wave-uniform base + lane*16
static __device__ __forceinline__ void async_ld16(u16* lds, const u16* g) {
  __builtin_amdgcn_global_load_lds(
      (const __attribute__((address_space(1))) void*)(const void*)g,
      (__attribute__((address_space(3))) void*)(void*)lds, 16, 0, 0);
}

// ---------------- elementwise fp32 -> bf16 hi/lo split ----------------
__global__ __launch_bounds__(256) void split_pair_kernel(
    const float* __restrict__ in, u16* __restrict__ hi, u16* __restrict__ lo,
    int n) {
  int idx = (blockIdx.x * 256 + threadIdx.x) * 4;
  if (idx >= n) return;
  float4 v = *(const float4*)(in + idx);
  u16 h0, h1, h2, h3, l0, l1, l2, l3;
  split_bf16(v.x, h0, l0);
  split_bf16(v.y, h1, l1);
  split_bf16(v.z, h2, l2);
  split_bf16(v.w, h3, l3);
  u16x4 h = {h0, h1, h2, h3};
  u16x4 l = {l0, l1, l2, l3};
  *(u16x4*)(hi + idx) = h;
  *(u16x4*)(lo + idx) = l;
}

// ---------------- QKV projection GEMM (split-bf16 MFMA, 3-term) ----------
// C[4096,3072] = x[4096,1024] @ qkv_w[3072,1024]^T + b, epilogue scatters to
// Q,K [bh][s][64] hi/lo and transposed V [bh][d][s] hi/lo.
__global__ __launch_bounds__(256) void qkv_gemm_mfma(
    const u16* __restrict__ xh, const u16* __restrict__ xl,
    const u16* __restrict__ wh, const u16* __restrict__ wl,
    const float* __restrict__ bias, u16* __restrict__ Qhi,
    u16* __restrict__ Qlo, u16* __restrict__ Khi, u16* __restrict__ Klo,
    u16* __restrict__ Vthi, u16* __restrict__ Vtlo) {
  __shared__ __align__(16) u16 Ah[4096], Al[4096], Bh[4096], Bl[4096];
  const int tid = threadIdx.x;
  const int w = tid >> 6, lane = tid & 63;
  const int m = lane & 15, quad = lane >> 4;
  const int wm = w >> 1, wn = w & 1;
  const int m0 = blockIdx.x * 128, n0 = blockIdx.y * 128;
  const int rl = lane >> 2, bp = lane & 3;
  const int sst = (rl >> 1) & 3;                 // staging swizzle
  const int sa = (quad ^ ((m >> 1) & 3)) * 8;    // fragment-read swizzle

  f32x4 acc[4][4];
  const f32x4 vzero = {0.f, 0.f, 0.f, 0.f};
#pragma unroll
  for (int mt = 0; mt < 4; ++mt)
#pragma unroll
    for (int nt = 0; nt < 4; ++nt) acc[mt][nt] = vzero;

  for (int k0 = 0; k0 < DMODEL; k0 += 32) {
#pragma unroll
    for (int i = 0; i < 2; ++i) {
      int cc = w * 2 + i;
      int row = cc * 16 + rl;
      int gofs = k0 + ((bp ^ sst) << 3);
      async_ld16(&Ah[cc * 512], xh + (m0 + row) * DMODEL + gofs);
      async_ld16(&Al[cc * 512], xl + (m0 + row) * DMODEL + gofs);
      async_ld16(&Bh[cc * 512], wh + (n0 + row) * DMODEL + gofs);
      async_ld16(&Bl[cc * 512], wl + (n0 + row) * DMODEL + gofs);
    }
    __syncthreads();
    bf16x8 afh[4], afl[4], bfh[4], bfl[4];
#pragma unroll
    for (int t = 0; t < 4; ++t) {
      int ra = (wm * 64 + t * 16 + m) * 32 + sa;
      afh[t] = *(const bf16x8*)&Ah[ra];
      afl[t] = *(const bf16x8*)&Al[ra];
      int rb = (wn * 64 + t * 16 + m) * 32 + sa;
      bfh[t] = *(const bf16x8*)&Bh[rb];
      bfl[t] = *(const bf16x8*)&Bl[rb];
    }
#pragma unroll
    for (int mt = 0; mt < 4; ++mt)
#pragma unroll
      for (int nt = 0; nt < 4; ++nt) {
        acc[mt][nt] = MFMA(afh[mt], bfh[nt], acc[mt][nt]);
        acc[mt][nt] = MFMA(afh[mt], bfl[nt], acc[mt][nt]);
        acc[mt][nt] = MFMA(afl[mt], bfh[nt], acc[mt][nt]);
      }
    __syncthreads();
  }
  // epilogue: bias, split, scatter
#pragma unroll
  for (int mt = 0; mt < 4; ++mt) {
#pragma unroll
    for (int rg = 0; rg < 4; ++rg) {
      int grow = m0 + wm * 64 + mt * 16 + quad * 4 + rg;
      int bb = grow >> 11, s = grow & (S_LEN - 1);
#pragma unroll
      for (int nt = 0; nt < 4; ++nt) {
        int e = n0 + wn * 64 + nt * 16 + m;
        float val = acc[mt][nt][rg] + bias[e];
        int h = e / 192;
        int r = e - h * 192;
        int d = r & 63;
        int bh = bb * NH + h;
        u16 hi, lo;
        split_bf16(val, hi, lo);
        if (r < 64) {
          int off = (bh * S_LEN + s) * HDIM + d;
          Qhi[off] = hi; Qlo[off] = lo;
        } else if (r < 128) {
          int off = (bh * S_LEN + s) * HDIM + d;
          Khi[off] = hi; Klo[off] = lo;
        } else {
          int off = (bh * HDIM + d) * S_LEN + s;
          Vthi[off] = hi; Vtlo[off] = lo;
        }
      }
    }
  }
}

// ---------------- Output projection GEMM (split-bf16 MFMA, 3-term) --------
// out[4096,1024] = values[4096,1024] @ o_w[1024,1024]^T + o_b (fp32 out).
// A (values) comes pre-split; B (o_w) is split on the fly during staging.
__global__ __launch_bounds__(256) void o_gemm_mfma(
    const u16* __restrict__ valh, const u16* __restrict__ vall,
    const float* __restrict__ ow, const float* __restrict__ bias,
    float* __restrict__ out) {
  __shared__ __align__(16) u16 Ah[4096], Al[4096], Bh[4096], Bl[4096];
  const int tid = threadIdx.x;
  const int w = tid >> 6, lane = tid & 63;
  const int m = lane & 15, quad = lane >> 4;
  const int wm = w >> 1, wn = w & 1;
  const int m0 = blockIdx.x * 128, n0 = blockIdx.y * 128;
  const int rl = lane >> 2, bp = lane & 3;
  const int sst = (rl >> 1) & 3;
  const int sa = (quad ^ ((m >> 1) & 3)) * 8;
  const int rB = tid >> 1, hf = tid & 1;
  const int sB = (rB >> 1) & 3;

  f32x4 acc[4][4];
  const f32x4 vzero = {0.f, 0.f, 0.f, 0.f};
#pragma unroll
  for (int mt = 0; mt < 4; ++mt)
#pragma unroll
    for (int nt = 0; nt < 4; ++nt) acc[mt][nt] = vzero;

  for (int k0 = 0; k0 < DMODEL; k0 += 32) {
#pragma unroll
    for (int i = 0; i < 2; ++i) {
      int cc = w * 2 + i;
      int row = cc * 16 + rl;
      int gofs = k0 + ((bp ^ sst) << 3);
      async_ld16(&Ah[cc * 512], valh + (m0 + row) * DMODEL + gofs);
      async_ld16(&Al[cc * 512], vall + (m0 + row) * DMODEL + gofs);
    }
    {
      const float* src = ow + (n0 + rB) * DMODEL + k0 + hf * 16;
      float tmp[16];
      *(float4*)&tmp[0] = *(const float4*)(src);
      *(float4*)&tmp[4] = *(const float4*)(src + 4);
      *(float4*)&tmp[8] = *(const float4*)(src + 8);
      *(float4*)&tmp[12] = *(const float4*)(src + 12);
      u16 hbuf[16], lbuf[16];
#pragma unroll
      for (int ii = 0; ii < 16; ++ii) split_bf16(tmp[ii], hbuf[ii], lbuf[ii]);
#pragma unroll
      for (int j = 0; j < 2; ++j) {
        int bs = ((2 * hf + j) ^ sB) * 8;
        bf16x8 hv, lv;
#pragma unroll
        for (int q2 = 0; q2 < 8; ++q2) {
          hv[q2] = (short)hbuf[j * 8 + q2];
          lv[q2] = (short)lbuf[j * 8 + q2];
        }
        *(bf16x8*)&Bh[rB * 32 + bs] = hv;
        *(bf16x8*)&Bl[rB * 32 + bs] = lv;
      }
    }
    __syncthreads();
    bf16x8 afh[4], afl[4], bfh[4], bfl[4];
#pragma unroll
    for (int t = 0; t < 4; ++t) {
      int ra = (wm * 64 + t * 16 + m) * 32 + sa;
      afh[t] = *(const bf16x8*)&Ah[ra];
      afl[t] = *(const bf16x8*)&Al[ra];
      int rb = (wn * 64 + t * 16 + m) * 32 + sa;
      bfh[t] = *(const bf16x8*)&Bh[rb];
      bfl[t] = *(const bf16x8*)&Bl[rb];
    }
#pragma unroll
    for (int mt = 0; mt < 4; ++mt)
#pragma unroll
      for (int nt = 0; nt < 4; ++nt) {
        acc[mt][nt] = MFMA(afh[mt], bfh[nt], acc[mt][nt]);
        acc[mt][nt] = MFMA(afh[mt], bfl[nt], acc[mt][nt]);
        acc[mt][nt] = MFMA(afl[mt], bfh[nt], acc[mt][nt]);
      }
    __syncthreads();
  }
#pragma unroll
  for (int mt = 0; mt < 4; ++mt) {
#pragma unroll
    for (int rg = 0; rg < 4; ++rg) {
      int grow = m0 + wm * 64 + mt * 16 + quad * 4 + rg;
#pragma unroll
      for (int nt = 0; nt < 4; ++nt) {
        int e = n0 + wn * 64 + nt * 16 + m;
        out[(size_t)grow * DMODEL + e] = acc[mt][nt][rg] + bias[e];
      }
    }
  }
}

// Per-(b,h) column sums of V (from transposed hi/lo), for all-pruned fallback.
__global__ __launch_bounds__(256) void vsum_kernel(
    const u16* __restrict__ Vthi, const u16* __restrict__ Vtlo,
    float* __restrict__ vsum) {
  const int bh = blockIdx.x;
  const int tid = threadIdx.x;
  const int d = tid >> 2, part = tid & 3;
  int base = (bh * HDIM + d) * S_LEN + part * 512;
  float s = 0.f;
  for (int k = 0; k < 512; ++k) s += bf2f(Vthi[base + k]) + bf2f(Vtlo[base + k]);
  __shared__ float red[64][4];
  red[d][part] = s;
  __syncthreads();
  if (part == 0)
    vsum[bh * HDIM + d] = red[d][0] + red[d][1] + red[d][2] + red[d][3];
}

// Fused two-pass pruned attention, split-bf16 MFMA, LDS-staged K/V.
// Block = (b,h, 64-query tile); 4 waves; wave owns 16 q rows.
__global__ __launch_bounds__(256) void attn_mfma_kernel(
    const u16* __restrict__ Qhi, const u16* __restrict__ Qlo,
    const u16* __restrict__ Khi, const u16* __restrict__ Klo,
    const u16* __restrict__ Vthi, const u16* __restrict__ Vtlo,
    const float* __restrict__ thr, const float* __restrict__ vsum,
    u16* __restrict__ valh, u16* __restrict__ vall) {
  const int blk = blockIdx.x;
  const int qt = blk & 31, bh = blk >> 5;
  const int h = bh & (NH - 1), bb = bh >> 4;
  const int tid = threadIdx.x;
  const int w = tid >> 6, lane = tid & 63;
  const int m = lane & 15, quad = lane >> 4;
  const int rsub = lane >> 3;                    // 0..7: row within 8-row chunk
  const int bsw = (lane & 7) ^ rsub;             // swizzled 16B-block index

  // 64KB total LDS: K double-buffered, V single, P hi/lo staging
  __shared__ __align__(16) u16 Kh_s[2][4096];
  __shared__ __align__(16) u16 Kl_s[2][4096];
  __shared__ __align__(16) u16 Vh_s[4096];
  __shared__ __align__(16) u16 Vl_s[4096];
  __shared__ __align__(16) u16 Phi_s[4][16][64];
  __shared__ __align__(16) u16 Plo_s[4][16][64];

  // persistent Q fragments (A-operand: A[m=lane&15][k=quad*8+j])
  const int qoff = (bh * S_LEN + qt * 64 + w * 16 + m) * HDIM + quad * 8;
  const bf16x8 aQh0 = *(const bf16x8*)(Qhi + qoff);
  const bf16x8 aQh1 = *(const bf16x8*)(Qhi + qoff + 32);
  const bf16x8 aQl0 = *(const bf16x8*)(Qlo + qoff);
  const bf16x8 aQl1 = *(const bf16x8*)(Qlo + qoff + 32);

  const u16* KhT = Khi + bh * S_LEN * HDIM;
  const u16* KlT = Klo + bh * S_LEN * HDIM;
  const u16* VhT = Vthi + bh * HDIM * S_LEN;
  const u16* VlT = Vtlo + bh * HDIM * S_LEN;
  const float th = thr[h];

  // swizzled read offsets (within a 64-short row; depends only on lane)
  const int s0 = (quad ^ (m & 7)) * 8;
  const int s1 = ((4 + quad) ^ (m & 7)) * 8;

  float mr[4], Zr[4], Z2r[4], tzr[4];
#pragma unroll
  for (int r = 0; r < 4; ++r) { mr[r] = -INFINITY; Zr[r] = 0.f; Z2r[r] = 0.f; }

  const f32x4 vzero = {0.f, 0.f, 0.f, 0.f};

  // stage helpers: each wave stages chunks {2w, 2w+1} of each 8KB tile
#define STAGE_K(bufi, t)                                                     \
  {                                                                          \
    const u16* gh = KhT + (t) * 64 * 64;                                     \
    const u16* gl = KlT + (t) * 64 * 64;                                     \
    _Pragma("unroll") for (int i = 0; i < 2; ++i) {                          \
      int c = w * 2 + i;                                                     \
      int row = c * 8 + rsub;                                                \
      async_ld16(&Kh_s[bufi][c * 512], gh + row * 64 + bsw * 8);             \
      async_ld16(&Kl_s[bufi][c * 512], gl + row * 64 + bsw * 8);             \
    }                                                                        \
  }
#define STAGE_V(t)                                                           \
  {                                                                          \
    _Pragma("unroll") for (int i = 0; i < 2; ++i) {                          \
      int c = w * 2 + i;                                                     \
      int row = c * 8 + rsub;                                                \
      async_ld16(&Vh_s[c * 512], VhT + row * 2048 + (t) * 64 + bsw * 8);     \
      async_ld16(&Vl_s[c * 512], VlT + row * 2048 + (t) * 64 + bsw * 8);     \
    }                                                                        \
  }

  // ---------------- pass 1: row max + denominator ----------------
  STAGE_K(0, 0);
  __syncthreads();
  for (int t = 0; t < 32; ++t) {
    const int cur = t & 1;
    if (t < 31) STAGE_K(cur ^ 1, t + 1);
    f32x4 acc[4];
#pragma unroll
    for (int nt = 0; nt < 4; ++nt) acc[nt] = vzero;
#pragma unroll
    for (int nt = 0; nt < 4; ++nt) {
      const int ro = (nt * 16 + m) * 64;
      bf16x8 kh0 = *(const bf16x8*)&Kh_s[cur][ro + s0];
      bf16x8 kh1 = *(const bf16x8*)&Kh_s[cur][ro + s1];
      bf16x8 kl0 = *(const bf16x8*)&Kl_s[cur][ro + s0];
      bf16x8 kl1 = *(const bf16x8*)&Kl_s[cur][ro + s1];
      acc[nt] = MFMA(aQh0, kh0, acc[nt]);
      acc[nt] = MFMA(aQh1, kh1, acc[nt]);
      acc[nt] = MFMA(aQh0, kl0, acc[nt]);
      acc[nt] = MFMA(aQh1, kl1, acc[nt]);
      acc[nt] = MFMA(aQl0, kh0, acc[nt]);
      acc[nt] = MFMA(aQl1, kh1, acc[nt]);
      acc[nt] = MFMA(aQl0, kl0, acc[nt]);
      acc[nt] = MFMA(aQl1, kl1, acc[nt]);
    }
#pragma unroll
    for (int r = 0; r < 4; ++r) {
      float l0 = acc[0][r] * SCALE, l1 = acc[1][r] * SCALE;
      float l2 = acc[2][r] * SCALE, l3 = acc[3][r] * SCALE;
      float tmax = qredmax(fmaxf(fmaxf(l0, l1), fmaxf(l2, l3)));
      float mnew = fmaxf(mr[r], tmax);
      float es = __expf(l0 - mnew) + __expf(l1 - mnew) + __expf(l2 - mnew) +
                 __expf(l3 - mnew);
      es = qredsum(es);
      Zr[r] = Zr[r] * __expf(mr[r] - mnew) + es;
      mr[r] = mnew;
    }
    __syncthreads();
  }
#pragma unroll
  for (int r = 0; r < 4; ++r) tzr[r] = th * Zr[r];

  // ---------------- pass 2: masked softmax + PV ----------------
  f32x4 oacc[4];
#pragma unroll
  for (int nt = 0; nt < 4; ++nt) oacc[nt] = vzero;

  STAGE_K(0, 0);
  __syncthreads();
  for (int t = 0; t < 32; ++t) {
    const int cur = t & 1;
    STAGE_V(t);
    if (t < 31) STAGE_K(cur ^ 1, t + 1);
    f32x4 acc[4];
#pragma unroll
    for (int nt = 0; nt < 4; ++nt) acc[nt] = vzero;
#pragma unroll
    for (int nt = 0; nt < 4; ++nt) {
      const int ro = (nt * 16 + m) * 64;
      bf16x8 kh0 = *(const bf16x8*)&Kh_s[cur][ro + s0];
      bf16x8 kh1 = *(const bf16x8*)&Kh_s[cur][ro + s1];
      bf16x8 kl0 = *(const bf16x8*)&Kl_s[cur][ro + s0];
      bf16x8 kl1 = *(const bf16x8*)&Kl_s[cur][ro + s1];
      acc[nt] = MFMA(aQh0, kh0, acc[nt]);
      acc[nt] = MFMA(aQh1, kh1, acc[nt]);
      acc[nt] = MFMA(aQh0, kl0, acc[nt]);
      acc[nt] = MFMA(aQh1, kl1, acc[nt]);
      acc[nt] = MFMA(aQl0, kh0, acc[nt]);
      acc[nt] = MFMA(aQl1, kh1, acc[nt]);
      acc[nt] = MFMA(aQl0, kl0, acc[nt]);
      acc[nt] = MFMA(aQl1, kl1, acc[nt]);
    }
    // prune + stage P (hi/lo) into xor-swizzled per-wave LDS
#pragma unroll
    for (int r = 0; r < 4; ++r) {
      int row = quad * 4 + r;
      float psum = 0.f;
#pragma unroll
      for (int nt = 0; nt < 4; ++nt) {
        float pu = __expf(acc[nt][r] * SCALE - mr[r]);
        float p = (pu > tzr[r]) ? pu : 0.f;
        psum += p;
        int col = nt * 16 + m;
        int cs = (((col >> 3) ^ (row & 7)) << 3) | (col & 7);
        u16 phi_u, plo_u;
        split_bf16(p, phi_u, plo_u);
        Phi_s[w][row][cs] = phi_u;
        Plo_s[w][row][cs] = plo_u;
      }
      Z2r[r] += psum;  // lane-local partial; reduced once in epilogue
    }
    __syncthreads();  // V(t) (and K(t+1)) staged; P visible (per-wave anyway)
    // P A-fragments from swizzled LDS (conflict-free b128)
    int b0 = ((quad) ^ (m & 7)) * 8;
    int b1 = ((4 + quad) ^ (m & 7)) * 8;
    bf16x8 aPh0 = *(const bf16x8*)&Phi_s[w][m][b0];
    bf16x8 aPh1 = *(const bf16x8*)&Phi_s[w][m][b1];
    bf16x8 aPl0 = *(const bf16x8*)&Plo_s[w][m][b0];
    bf16x8 aPl1 = *(const bf16x8*)&Plo_s[w][m][b1];
    // PV: B-operand from LDS-staged transposed V (B[n=d][k=key])
#pragma unroll
    for (int nt = 0; nt < 4; ++nt) {
      const int ro = (nt * 16 + m) * 64;
      bf16x8 vh0 = *(const bf16x8*)&Vh_s[ro + s0];
      bf16x8 vh1 = *(const bf16x8*)&Vh_s[ro + s1];
      bf16x8 vl0 = *(const bf16x8*)&Vl_s[ro + s0];
      bf16x8 vl1 = *(const bf16x8*)&Vl_s[ro + s1];
      oacc[nt] = MFMA(aPh0, vh0, oacc[nt]);
      oacc[nt] = MFMA(aPh1, vh1, oacc[nt]);
      oacc[nt] = MFMA(aPh0, vl0, oacc[nt]);
      oacc[nt] = MFMA(aPh1, vl1, oacc[nt]);
      oacc[nt] = MFMA(aPl0, vh0, oacc[nt]);
      oacc[nt] = MFMA(aPl1, vh1, oacc[nt]);
    }
    __syncthreads();  // all waves done with V buf / K[cur] before restage
  }

  // ---------------- epilogue: normalize (or uniform fallback), write -------
#pragma unroll
  for (int r = 0; r < 4; ++r) {
    float z2 = qredsum(Z2r[r]);
    float invz = (z2 > 0.f) ? (1.f / z2) : 0.f;
    int srow = qt * 64 + w * 16 + quad * 4 + r;
#pragma unroll
    for (int nt = 0; nt < 4; ++nt) {
      float vs = vsum[bh * HDIM + nt * 16 + m];
      float o = (z2 > 0.f) ? (oacc[nt][r] * invz) : (vs * (1.0f / S_LEN));
      int idx = (bb * S_LEN + srow) * DMODEL + h * HDIM + nt * 16 + m;
      u16 hi, lo;
      split_bf16(o, hi, lo);
      valh[idx] = hi;
      vall[idx] = lo;
    }
  }
}

extern "C" void kernel_launch(void* const* d_in, const int* in_sizes, int n_in,
                              void* d_out, int out_size, void* d_ws, size_t ws_size,
                              hipStream_t stream) {
  const float* x = (const float*)d_in[0];
  const float* thresholds = (const float*)d_in[1];
  const float* qkv_w = (const float*)d_in[2];
  const float* qkv_b = (const float*)d_in[3];
  const float* o_w = (const float*)d_in[4];
  const float* o_b = (const float*)d_in[5];

  const size_t NBH = (size_t)BATCH * NH * S_LEN * HDIM;  // 4194304
  u16* base = (u16*)d_ws;
  u16* Qhi = base;
  u16* Qlo = base + NBH;
  u16* Khi = base + 2 * NBH;
  u16* Klo = base + 3 * NBH;
  u16* Vthi = base + 4 * NBH;
  u16* Vtlo = base + 5 * NBH;
  float* vsum = (float*)(base + 6 * NBH);  // 2048 floats
  u16* R1 = (u16*)(vsum + 2048);           // 8M u16: x splits, then values
  u16* xh = R1;
  u16* xl = R1 + NBH;
  u16* valh = R1;       // aliases xh/xl after qkv_gemm is done with x
  u16* vall = R1 + NBH;
  // qkv_w splits live in d_out (dead by the time o_gemm writes the output)
  u16* wh = (u16*)d_out;
  u16* wl = wh + (size_t)3 * DMODEL * DMODEL;

  split_pair_kernel<<<4096, 256, 0, stream>>>(x, xh, xl, (int)NBH);
  split_pair_kernel<<<3072, 256, 0, stream>>>(qkv_w, wh, wl, 3 * DMODEL * DMODEL);
  dim3 g1(32, 24);
  qkv_gemm_mfma<<<g1, 256, 0, stream>>>(xh, xl, wh, wl, qkv_b, Qhi, Qlo, Khi,
                                        Klo, Vthi, Vtlo);
  vsum_kernel<<<BATCH * NH, 256, 0, stream>>>(Vthi, Vtlo, vsum);
  attn_mfma_kernel<<<BATCH * NH * (S_LEN / 64), 256, 0, stream>>>(
      Qhi, Qlo, Khi, Klo, Vthi, Vtlo, thresholds, vsum, valh, vall);
  dim3 g3(32, 8);
  o_gemm_mfma<<<g3, 256, 0, stream>>>(valh, vall, o_w, o_b, (float*)d_out);
}

// Round 6
// 513.518 us; speedup vs baseline: 2.8993x; 1.0685x over previous
//
#include <hip/hip_runtime.h>
#include <math.h>

#define BATCH 2
#define S_LEN 2048
#define DMODEL 1024
#define NH 16
#define HDIM 64
#define SCALE 0.125f

typedef short bf16x8 __attribute__((ext_vector_type(8)));
typedef float f32x4 __attribute__((ext_vector_type(4)));
typedef unsigned short u16;
typedef unsigned short u16x4 __attribute__((ext_vector_type(4)));
#define MFMA(a, b, c) __builtin_amdgcn_mfma_f32_16x16x32_bf16(a, b, c, 0, 0, 0)

static __device__ __forceinline__ float bf2f(u16 u) {
  return __uint_as_float(((unsigned int)u) << 16);
}

// round-to-nearest-even split: a ~= hi + lo, both bf16
static __device__ __forceinline__ void split_bf16(float a, u16& hi, u16& lo) {
  unsigned int u = __float_as_uint(a);
  unsigned int r = (u + 0x7fffu + ((u >> 16) & 1u)) >> 16;
  hi = (u16)r;
  float res = a - __uint_as_float(r << 16);
  unsigned int u2 = __float_as_uint(res);
  lo = (u16)((u2 + 0x7fffu + ((u2 >> 16) & 1u)) >> 16);
}

static __device__ __forceinline__ float qredsum(float v) {
#pragma unroll
  for (int off = 8; off >= 1; off >>= 1) v += __shfl_xor(v, off, 16);
  return v;
}

// async global->LDS, 16B per lane; LDS dest = wave-uniform base + lane*16
static __device__ __forceinline__ void async_ld16(u16* lds, const u16* g) {
  __builtin_amdgcn_global_load_lds(
      (const __attribute__((address_space(1))) void*)(const void*)g,
      (__attribute__((address_space(3))) void*)(void*)lds, 16, 0, 0);
}

// ---------------- elementwise fp32 -> bf16 hi/lo split ----------------
__global__ __launch_bounds__(256) void split_pair_kernel(
    const float* __restrict__ in, u16* __restrict__ hi, u16* __restrict__ lo,
    int n) {
  int idx = (blockIdx.x * 256 + threadIdx.x) * 4;
  if (idx >= n) return;
  float4 v = *(const float4*)(in + idx);
  u16 h0, h1, h2, h3, l0, l1, l2, l3;
  split_bf16(v.x, h0, l0);
  split_bf16(v.y, h1, l1);
  split_bf16(v.z, h2, l2);
  split_bf16(v.w, h3, l3);
  u16x4 h = {h0, h1, h2, h3};
  u16x4 l = {l0, l1, l2, l3};
  *(u16x4*)(hi + idx) = h;
  *(u16x4*)(lo + idx) = l;
}

// ---------------- QKV projection GEMM (split-bf16 MFMA, 3-term) ----------
// C[4096,3072] = x[4096,1024] @ qkv_w[3072,1024]^T + b, epilogue scatters to
// Q,K [bh][s][64] hi/lo and transposed V [bh][d][s] hi/lo.
__global__ __launch_bounds__(256) void qkv_gemm_mfma(
    const u16* __restrict__ xh, const u16* __restrict__ xl,
    const u16* __restrict__ wh, const u16* __restrict__ wl,
    const float* __restrict__ bias, u16* __restrict__ Qhi,
    u16* __restrict__ Qlo, u16* __restrict__ Khi, u16* __restrict__ Klo,
    u16* __restrict__ Vthi, u16* __restrict__ Vtlo) {
  __shared__ __align__(16) u16 Ah[4096], Al[4096], Bh[4096], Bl[4096];
  const int tid = threadIdx.x;
  const int w = tid >> 6, lane = tid & 63;
  const int m = lane & 15, quad = lane >> 4;
  const int wm = w >> 1, wn = w & 1;
  const int m0 = blockIdx.x * 128, n0 = blockIdx.y * 128;
  const int rl = lane >> 2, bp = lane & 3;
  const int sst = (rl >> 1) & 3;                 // staging swizzle
  const int sa = (quad ^ ((m >> 1) & 3)) * 8;    // fragment-read swizzle

  f32x4 acc[4][4];
  const f32x4 vzero = {0.f, 0.f, 0.f, 0.f};
#pragma unroll
  for (int mt = 0; mt < 4; ++mt)
#pragma unroll
    for (int nt = 0; nt < 4; ++nt) acc[mt][nt] = vzero;

  for (int k0 = 0; k0 < DMODEL; k0 += 32) {
#pragma unroll
    for (int i = 0; i < 2; ++i) {
      int cc = w * 2 + i;
      int row = cc * 16 + rl;
      int gofs = k0 + ((bp ^ sst) << 3);
      async_ld16(&Ah[cc * 512], xh + (m0 + row) * DMODEL + gofs);
      async_ld16(&Al[cc * 512], xl + (m0 + row) * DMODEL + gofs);
      async_ld16(&Bh[cc * 512], wh + (n0 + row) * DMODEL + gofs);
      async_ld16(&Bl[cc * 512], wl + (n0 + row) * DMODEL + gofs);
    }
    __syncthreads();
    bf16x8 afh[4], afl[4], bfh[4], bfl[4];
#pragma unroll
    for (int t = 0; t < 4; ++t) {
      int ra = (wm * 64 + t * 16 + m) * 32 + sa;
      afh[t] = *(const bf16x8*)&Ah[ra];
      afl[t] = *(const bf16x8*)&Al[ra];
      int rb = (wn * 64 + t * 16 + m) * 32 + sa;
      bfh[t] = *(const bf16x8*)&Bh[rb];
      bfl[t] = *(const bf16x8*)&Bl[rb];
    }
#pragma unroll
    for (int mt = 0; mt < 4; ++mt)
#pragma unroll
      for (int nt = 0; nt < 4; ++nt) {
        acc[mt][nt] = MFMA(afh[mt], bfh[nt], acc[mt][nt]);
        acc[mt][nt] = MFMA(afh[mt], bfl[nt], acc[mt][nt]);
        acc[mt][nt] = MFMA(afl[mt], bfh[nt], acc[mt][nt]);
      }
    __syncthreads();
  }
  // epilogue: bias, split, scatter
#pragma unroll
  for (int mt = 0; mt < 4; ++mt) {
#pragma unroll
    for (int rg = 0; rg < 4; ++rg) {
      int grow = m0 + wm * 64 + mt * 16 + quad * 4 + rg;
      int bb = grow >> 11, s = grow & (S_LEN - 1);
#pragma unroll
      for (int nt = 0; nt < 4; ++nt) {
        int e = n0 + wn * 64 + nt * 16 + m;
        float val = acc[mt][nt][rg] + bias[e];
        int h = e / 192;
        int r = e - h * 192;
        int d = r & 63;
        int bh = bb * NH + h;
        u16 hi, lo;
        split_bf16(val, hi, lo);
        if (r < 64) {
          int off = (bh * S_LEN + s) * HDIM + d;
          Qhi[off] = hi; Qlo[off] = lo;
        } else if (r < 128) {
          int off = (bh * S_LEN + s) * HDIM + d;
          Khi[off] = hi; Klo[off] = lo;
        } else {
          int off = (bh * HDIM + d) * S_LEN + s;
          Vthi[off] = hi; Vtlo[off] = lo;
        }
      }
    }
  }
}

// ---------------- Output projection GEMM (split-bf16 MFMA, 3-term) --------
// out[4096,1024] = values[4096,1024] @ o_w[1024,1024]^T + o_b (fp32 out).
// A (values) comes pre-split; B (o_w) is split on the fly during staging.
__global__ __launch_bounds__(256) void o_gemm_mfma(
    const u16* __restrict__ valh, const u16* __restrict__ vall,
    const float* __restrict__ ow, const float* __restrict__ bias,
    float* __restrict__ out) {
  __shared__ __align__(16) u16 Ah[4096], Al[4096], Bh[4096], Bl[4096];
  const int tid = threadIdx.x;
  const int w = tid >> 6, lane = tid & 63;
  const int m = lane & 15, quad = lane >> 4;
  const int wm = w >> 1, wn = w & 1;
  const int m0 = blockIdx.x * 128, n0 = blockIdx.y * 128;
  const int rl = lane >> 2, bp = lane & 3;
  const int sst = (rl >> 1) & 3;
  const int sa = (quad ^ ((m >> 1) & 3)) * 8;
  const int rB = tid >> 1, hf = tid & 1;
  const int sB = (rB >> 1) & 3;

  f32x4 acc[4][4];
  const f32x4 vzero = {0.f, 0.f, 0.f, 0.f};
#pragma unroll
  for (int mt = 0; mt < 4; ++mt)
#pragma unroll
    for (int nt = 0; nt < 4; ++nt) acc[mt][nt] = vzero;

  for (int k0 = 0; k0 < DMODEL; k0 += 32) {
#pragma unroll
    for (int i = 0; i < 2; ++i) {
      int cc = w * 2 + i;
      int row = cc * 16 + rl;
      int gofs = k0 + ((bp ^ sst) << 3);
      async_ld16(&Ah[cc * 512], valh + (m0 + row) * DMODEL + gofs);
      async_ld16(&Al[cc * 512], vall + (m0 + row) * DMODEL + gofs);
    }
    {
      const float* src = ow + (n0 + rB) * DMODEL + k0 + hf * 16;
      float tmp[16];
      *(float4*)&tmp[0] = *(const float4*)(src);
      *(float4*)&tmp[4] = *(const float4*)(src + 4);
      *(float4*)&tmp[8] = *(const float4*)(src + 8);
      *(float4*)&tmp[12] = *(const float4*)(src + 12);
      u16 hbuf[16], lbuf[16];
#pragma unroll
      for (int ii = 0; ii < 16; ++ii) split_bf16(tmp[ii], hbuf[ii], lbuf[ii]);
#pragma unroll
      for (int j = 0; j < 2; ++j) {
        int bs = ((2 * hf + j) ^ sB) * 8;
        bf16x8 hv, lv;
#pragma unroll
        for (int q2 = 0; q2 < 8; ++q2) {
          hv[q2] = (short)hbuf[j * 8 + q2];
          lv[q2] = (short)lbuf[j * 8 + q2];
        }
        *(bf16x8*)&Bh[rB * 32 + bs] = hv;
        *(bf16x8*)&Bl[rB * 32 + bs] = lv;
      }
    }
    __syncthreads();
    bf16x8 afh[4], afl[4], bfh[4], bfl[4];
#pragma unroll
    for (int t = 0; t < 4; ++t) {
      int ra = (wm * 64 + t * 16 + m) * 32 + sa;
      afh[t] = *(const bf16x8*)&Ah[ra];
      afl[t] = *(const bf16x8*)&Al[ra];
      int rb = (wn * 64 + t * 16 + m) * 32 + sa;
      bfh[t] = *(const bf16x8*)&Bh[rb];
      bfl[t] = *(const bf16x8*)&Bl[rb];
    }
#pragma unroll
    for (int mt = 0; mt < 4; ++mt)
#pragma unroll
      for (int nt = 0; nt < 4; ++nt) {
        acc[mt][nt] = MFMA(afh[mt], bfh[nt], acc[mt][nt]);
        acc[mt][nt] = MFMA(afh[mt], bfl[nt], acc[mt][nt]);
        acc[mt][nt] = MFMA(afl[mt], bfh[nt], acc[mt][nt]);
      }
    __syncthreads();
  }
#pragma unroll
  for (int mt = 0; mt < 4; ++mt) {
#pragma unroll
    for (int rg = 0; rg < 4; ++rg) {
      int grow = m0 + wm * 64 + mt * 16 + quad * 4 + rg;
#pragma unroll
      for (int nt = 0; nt < 4; ++nt) {
        int e = n0 + wn * 64 + nt * 16 + m;
        out[(size_t)grow * DMODEL + e] = acc[mt][nt][rg] + bias[e];
      }
    }
  }
}

// Per-(b,h) column sums of V (from transposed hi/lo), for all-pruned fallback.
__global__ __launch_bounds__(256) void vsum_kernel(
    const u16* __restrict__ Vthi, const u16* __restrict__ Vtlo,
    float* __restrict__ vsum) {
  const int bh = blockIdx.x;
  const int tid = threadIdx.x;
  const int d = tid >> 2, part = tid & 3;
  int base = (bh * HDIM + d) * S_LEN + part * 512;
  float s = 0.f;
  for (int k = 0; k < 512; k += 8) {
    bf16x8 vh = *(const bf16x8*)(Vthi + base + k);
    bf16x8 vl = *(const bf16x8*)(Vtlo + base + k);
#pragma unroll
    for (int j = 0; j < 8; ++j) s += bf2f((u16)vh[j]) + bf2f((u16)vl[j]);
  }
  __shared__ float red[64][4];
  red[d][part] = s;
  __syncthreads();
  if (part == 0)
    vsum[bh * HDIM + d] = red[d][0] + red[d][1] + red[d][2] + red[d][3];
}

// Fused two-pass pruned attention, split-bf16 MFMA, LDS-staged K/V.
// Logits are bounded (|l| ~< 4), so NO max subtraction: Z = sum(exp(l)),
// mask = exp(l) > t*Z — identical to softmax-threshold in exact math.
// Block = (b,h, 64-query tile); 4 waves; wave owns 16 q rows.
__global__ __launch_bounds__(256) void attn_mfma_kernel(
    const u16* __restrict__ Qhi, const u16* __restrict__ Qlo,
    const u16* __restrict__ Khi, const u16* __restrict__ Klo,
    const u16* __restrict__ Vthi, const u16* __restrict__ Vtlo,
    const float* __restrict__ thr, const float* __restrict__ vsum,
    u16* __restrict__ valh, u16* __restrict__ vall) {
  const int blk = blockIdx.x;
  const int qt = blk & 31, bh = blk >> 5;
  const int h = bh & (NH - 1), bb = bh >> 4;
  const int tid = threadIdx.x;
  const int w = tid >> 6, lane = tid & 63;
  const int m = lane & 15, quad = lane >> 4;
  const int rsub = lane >> 3;                    // 0..7: row within 8-row chunk
  const int bsw = (lane & 7) ^ rsub;             // swizzled 16B-block index

  // 64KB total LDS: K double-buffered, V single, P hi/lo staging
  __shared__ __align__(16) u16 Kh_s[2][4096];
  __shared__ __align__(16) u16 Kl_s[2][4096];
  __shared__ __align__(16) u16 Vh_s[4096];
  __shared__ __align__(16) u16 Vl_s[4096];
  __shared__ __align__(16) u16 Phi_s[4][16][64];
  __shared__ __align__(16) u16 Plo_s[4][16][64];

  // persistent Q fragments (A-operand: A[m=lane&15][k=quad*8+j])
  const int qoff = (bh * S_LEN + qt * 64 + w * 16 + m) * HDIM + quad * 8;
  const bf16x8 aQh0 = *(const bf16x8*)(Qhi + qoff);
  const bf16x8 aQh1 = *(const bf16x8*)(Qhi + qoff + 32);
  const bf16x8 aQl0 = *(const bf16x8*)(Qlo + qoff);
  const bf16x8 aQl1 = *(const bf16x8*)(Qlo + qoff + 32);

  const u16* KhT = Khi + bh * S_LEN * HDIM;
  const u16* KlT = Klo + bh * S_LEN * HDIM;
  const u16* VhT = Vthi + bh * HDIM * S_LEN;
  const u16* VlT = Vtlo + bh * HDIM * S_LEN;
  const float th = thr[h];

  // swizzled read offsets (within a 64-short row; depends only on lane)
  const int s0 = (quad ^ (m & 7)) * 8;
  const int s1 = ((4 + quad) ^ (m & 7)) * 8;

  float Zr[4], Z2r[4], tzr[4];
#pragma unroll
  for (int r = 0; r < 4; ++r) { Zr[r] = 0.f; Z2r[r] = 0.f; }

  const f32x4 vzero = {0.f, 0.f, 0.f, 0.f};

  // stage helpers: each wave stages chunks {2w, 2w+1} of each 8KB tile
#define STAGE_K(bufi, t)                                                     \
  {                                                                          \
    const u16* gh = KhT + (t) * 64 * 64;                                     \
    const u16* gl = KlT + (t) * 64 * 64;                                     \
    _Pragma("unroll") for (int i = 0; i < 2; ++i) {                          \
      int c = w * 2 + i;                                                     \
      int row = c * 8 + rsub;                                                \
      async_ld16(&Kh_s[bufi][c * 512], gh + row * 64 + bsw * 8);             \
      async_ld16(&Kl_s[bufi][c * 512], gl + row * 64 + bsw * 8);             \
    }                                                                        \
  }
#define STAGE_V(t)                                                           \
  {                                                                          \
    _Pragma("unroll") for (int i = 0; i < 2; ++i) {                          \
      int c = w * 2 + i;                                                     \
      int row = c * 8 + rsub;                                                \
      async_ld16(&Vh_s[c * 512], VhT + row * 2048 + (t) * 64 + bsw * 8);     \
      async_ld16(&Vl_s[c * 512], VlT + row * 2048 + (t) * 64 + bsw * 8);     \
    }                                                                        \
  }

  // ------- pass 1: denominator Z (lane-local, no cross-lane per tile) -----
  STAGE_K(0, 0);
  __syncthreads();
  for (int t = 0; t < 32; ++t) {
    const int cur = t & 1;
    if (t < 31) STAGE_K(cur ^ 1, t + 1);
    f32x4 acc[4];
#pragma unroll
    for (int nt = 0; nt < 4; ++nt) acc[nt] = vzero;
#pragma unroll
    for (int nt = 0; nt < 4; ++nt) {
      const int ro = (nt * 16 + m) * 64;
      bf16x8 kh0 = *(const bf16x8*)&Kh_s[cur][ro + s0];
      bf16x8 kh1 = *(const bf16x8*)&Kh_s[cur][ro + s1];
      bf16x8 kl0 = *(const bf16x8*)&Kl_s[cur][ro + s0];
      bf16x8 kl1 = *(const bf16x8*)&Kl_s[cur][ro + s1];
      acc[nt] = MFMA(aQh0, kh0, acc[nt]);
      acc[nt] = MFMA(aQh1, kh1, acc[nt]);
      acc[nt] = MFMA(aQh0, kl0, acc[nt]);
      acc[nt] = MFMA(aQh1, kl1, acc[nt]);
      acc[nt] = MFMA(aQl0, kh0, acc[nt]);
      acc[nt] = MFMA(aQl1, kh1, acc[nt]);
      acc[nt] = MFMA(aQl0, kl0, acc[nt]);
      acc[nt] = MFMA(aQl1, kl1, acc[nt]);
    }
#pragma unroll
    for (int r = 0; r < 4; ++r) {
      Zr[r] += __expf(acc[0][r] * SCALE) + __expf(acc[1][r] * SCALE) +
               __expf(acc[2][r] * SCALE) + __expf(acc[3][r] * SCALE);
    }
    __syncthreads();
  }
#pragma unroll
  for (int r = 0; r < 4; ++r) tzr[r] = th * qredsum(Zr[r]);

  // ---------------- pass 2: masked (pruned) softmax + PV ----------------
  f32x4 oacc[4];
#pragma unroll
  for (int nt = 0; nt < 4; ++nt) oacc[nt] = vzero;

  STAGE_K(0, 0);
  __syncthreads();
  for (int t = 0; t < 32; ++t) {
    const int cur = t & 1;
    STAGE_V(t);
    if (t < 31) STAGE_K(cur ^ 1, t + 1);
    f32x4 acc[4];
#pragma unroll
    for (int nt = 0; nt < 4; ++nt) acc[nt] = vzero;
#pragma unroll
    for (int nt = 0; nt < 4; ++nt) {
      const int ro = (nt * 16 + m) * 64;
      bf16x8 kh0 = *(const bf16x8*)&Kh_s[cur][ro + s0];
      bf16x8 kh1 = *(const bf16x8*)&Kh_s[cur][ro + s1];
      bf16x8 kl0 = *(const bf16x8*)&Kl_s[cur][ro + s0];
      bf16x8 kl1 = *(const bf16x8*)&Kl_s[cur][ro + s1];
      acc[nt] = MFMA(aQh0, kh0, acc[nt]);
      acc[nt] = MFMA(aQh1, kh1, acc[nt]);
      acc[nt] = MFMA(aQh0, kl0, acc[nt]);
      acc[nt] = MFMA(aQh1, kl1, acc[nt]);
      acc[nt] = MFMA(aQl0, kh0, acc[nt]);
      acc[nt] = MFMA(aQl1, kh1, acc[nt]);
      acc[nt] = MFMA(aQl0, kl0, acc[nt]);
      acc[nt] = MFMA(aQl1, kl1, acc[nt]);
    }
    // prune + stage P (hi/lo) into xor-swizzled per-wave LDS
#pragma unroll
    for (int r = 0; r < 4; ++r) {
      int row = quad * 4 + r;
      float psum = 0.f;
#pragma unroll
      for (int nt = 0; nt < 4; ++nt) {
        float pu = __expf(acc[nt][r] * SCALE);
        float p = (pu > tzr[r]) ? pu : 0.f;
        psum += p;
        int col = nt * 16 + m;
        int cs = (((col >> 3) ^ (row & 7)) << 3) | (col & 7);
        u16 phi_u, plo_u;
        split_bf16(p, phi_u, plo_u);
        Phi_s[w][row][cs] = phi_u;
        Plo_s[w][row][cs] = plo_u;
      }
      Z2r[r] += psum;  // lane-local partial; reduced once in epilogue
    }
    __syncthreads();  // V(t) (and K(t+1)) staged; P visible (per-wave anyway)
    // P A-fragments from swizzled LDS (conflict-free b128)
    int b0 = ((quad) ^ (m & 7)) * 8;
    int b1 = ((4 + quad) ^ (m & 7)) * 8;
    bf16x8 aPh0 = *(const bf16x8*)&Phi_s[w][m][b0];
    bf16x8 aPh1 = *(const bf16x8*)&Phi_s[w][m][b1];
    bf16x8 aPl0 = *(const bf16x8*)&Plo_s[w][m][b0];
    bf16x8 aPl1 = *(const bf16x8*)&Plo_s[w][m][b1];
    // PV: B-operand from LDS-staged transposed V (B[n=d][k=key])
#pragma unroll
    for (int nt = 0; nt < 4; ++nt) {
      const int ro = (nt * 16 + m) * 64;
      bf16x8 vh0 = *(const bf16x8*)&Vh_s[ro + s0];
      bf16x8 vh1 = *(const bf16x8*)&Vh_s[ro + s1];
      bf16x8 vl0 = *(const bf16x8*)&Vl_s[ro + s0];
      bf16x8 vl1 = *(const bf16x8*)&Vl_s[ro + s1];
      oacc[nt] = MFMA(aPh0, vh0, oacc[nt]);
      oacc[nt] = MFMA(aPh1, vh1, oacc[nt]);
      oacc[nt] = MFMA(aPh0, vl0, oacc[nt]);
      oacc[nt] = MFMA(aPh1, vl1, oacc[nt]);
      oacc[nt] = MFMA(aPl0, vh0, oacc[nt]);
      oacc[nt] = MFMA(aPl1, vh1, oacc[nt]);
    }
    __syncthreads();  // all waves done with V buf / K[cur] before restage
  }

  // ---------------- epilogue: normalize (or uniform fallback), write -------
#pragma unroll
  for (int r = 0; r < 4; ++r) {
    float z2 = qredsum(Z2r[r]);
    float invz = (z2 > 0.f) ? (1.f / z2) : 0.f;
    int srow = qt * 64 + w * 16 + quad * 4 + r;
#pragma unroll
    for (int nt = 0; nt < 4; ++nt) {
      float vs = vsum[bh * HDIM + nt * 16 + m];
      float o = (z2 > 0.f) ? (oacc[nt][r] * invz) : (vs * (1.0f / S_LEN));
      int idx = (bb * S_LEN + srow) * DMODEL + h * HDIM + nt * 16 + m;
      u16 hi, lo;
      split_bf16(o, hi, lo);
      valh[idx] = hi;
      vall[idx] = lo;
    }
  }
}

extern "C" void kernel_launch(void* const* d_in, const int* in_sizes, int n_in,
                              void* d_out, int out_size, void* d_ws, size_t ws_size,
                              hipStream_t stream) {
  const float* x = (const float*)d_in[0];
  const float* thresholds = (const float*)d_in[1];
  const float* qkv_w = (const float*)d_in[2];
  const float* qkv_b = (const float*)d_in[3];
  const float* o_w = (const float*)d_in[4];
  const float* o_b = (const float*)d_in[5];

  const size_t NBH = (size_t)BATCH * NH * S_LEN * HDIM;  // 4194304
  u16* base = (u16*)d_ws;
  u16* Qhi = base;
  u16* Qlo = base + NBH;
  u16* Khi = base + 2 * NBH;
  u16* Klo = base + 3 * NBH;
  u16* Vthi = base + 4 * NBH;
  u16* Vtlo = base + 5 * NBH;
  float* vsum = (float*)(base + 6 * NBH);  // 2048 floats
  u16* R1 = (u16*)(vsum + 2048);           // 8M u16: x splits, then values
  u16* xh = R1;
  u16* xl = R1 + NBH;
  u16* valh = R1;       // aliases xh/xl after qkv_gemm is done with x
  u16* vall = R1 + NBH;
  // qkv_w splits live in d_out (dead by the time o_gemm writes the output)
  u16* wh = (u16*)d_out;
  u16* wl = wh + (size_t)3 * DMODEL * DMODEL;

  split_pair_kernel<<<4096, 256, 0, stream>>>(x, xh, xl, (int)NBH);
  split_pair_kernel<<<3072, 256, 0, stream>>>(qkv_w, wh, wl, 3 * DMODEL * DMODEL);
  dim3 g1(32, 24);
  qkv_gemm_mfma<<<g1, 256, 0, stream>>>(xh, xl, wh, wl, qkv_b, Qhi, Qlo, Khi,
                                        Klo, Vthi, Vtlo);
  vsum_kernel<<<BATCH * NH, 256, 0, stream>>>(Vthi, Vtlo, vsum);
  attn_mfma_kernel<<<BATCH * NH * (S_LEN / 64), 256, 0, stream>>>(
      Qhi, Qlo, Khi, Klo, Vthi, Vtlo, thresholds, vsum, valh, vall);
  dim3 g3(32, 8);
  o_gemm_mfma<<<g3, 256, 0, stream>>>(valh, vall, o_w, o_b, (float*)d_out);
}

// Round 7
// 437.925 us; speedup vs baseline: 3.3997x; 1.1726x over previous
//
#include <hip/hip_runtime.h>
#include <math.h>

#define BATCH 2
#define S_LEN 2048
#define DMODEL 1024
#define NH 16
#define HDIM 64
#define SCALE 0.125f

typedef short bf16x8 __attribute__((ext_vector_type(8)));
typedef _Float16 f16x8 __attribute__((ext_vector_type(8)));
typedef float f32x4 __attribute__((ext_vector_type(4)));
typedef unsigned short u16;
typedef unsigned short u16x4 __attribute__((ext_vector_type(4)));
#define MFMA(a, b, c) __builtin_amdgcn_mfma_f32_16x16x32_bf16(a, b, c, 0, 0, 0)
#define MFMA16(a, b, c) __builtin_amdgcn_mfma_f32_16x16x32_f16(a, b, c, 0, 0, 0)

static __device__ __forceinline__ float bf2f(u16 u) {
  return __uint_as_float(((unsigned int)u) << 16);
}
static __device__ __forceinline__ u16 f2h_bits(float a) {
  _Float16 h = (_Float16)a;
  return *(u16*)&h;
}

// round-to-nearest-even split: a ~= hi + lo, both bf16
static __device__ __forceinline__ void split_bf16(float a, u16& hi, u16& lo) {
  unsigned int u = __float_as_uint(a);
  unsigned int r = (u + 0x7fffu + ((u >> 16) & 1u)) >> 16;
  hi = (u16)r;
  float res = a - __uint_as_float(r << 16);
  unsigned int u2 = __float_as_uint(res);
  lo = (u16)((u2 + 0x7fffu + ((u2 >> 16) & 1u)) >> 16);
}

static __device__ __forceinline__ float qredsum(float v) {
#pragma unroll
  for (int off = 8; off >= 1; off >>= 1) v += __shfl_xor(v, off, 16);
  return v;
}

// async global->LDS, 16B per lane; LDS dest = wave-uniform base + lane*16
static __device__ __forceinline__ void async_ld16(u16* lds, const u16* g) {
  __builtin_amdgcn_global_load_lds(
      (const __attribute__((address_space(1))) void*)(const void*)g,
      (__attribute__((address_space(3))) void*)(void*)lds, 16, 0, 0);
}

// ---------------- elementwise fp32 -> bf16 hi/lo split ----------------
__global__ __launch_bounds__(256) void split_pair_kernel(
    const float* __restrict__ in, u16* __restrict__ hi, u16* __restrict__ lo,
    int n) {
  int idx = (blockIdx.x * 256 + threadIdx.x) * 4;
  if (idx >= n) return;
  float4 v = *(const float4*)(in + idx);
  u16 h0, h1, h2, h3, l0, l1, l2, l3;
  split_bf16(v.x, h0, l0);
  split_bf16(v.y, h1, l1);
  split_bf16(v.z, h2, l2);
  split_bf16(v.w, h3, l3);
  u16x4 h = {h0, h1, h2, h3};
  u16x4 l = {l0, l1, l2, l3};
  *(u16x4*)(hi + idx) = h;
  *(u16x4*)(lo + idx) = l;
}

// ---------------- QKV projection GEMM (split-bf16 MFMA, 3-term) ----------
// Epilogue: Q,K bf16 hi/lo [bh][s][64]; V transposed single fp16 [bh][d][s].
__global__ __launch_bounds__(256) void qkv_gemm_mfma(
    const u16* __restrict__ xh, const u16* __restrict__ xl,
    const u16* __restrict__ wh, const u16* __restrict__ wl,
    const float* __restrict__ bias, u16* __restrict__ Qhi,
    u16* __restrict__ Qlo, u16* __restrict__ Khi, u16* __restrict__ Klo,
    u16* __restrict__ Vt) {
  __shared__ __align__(16) u16 Ah[4096], Al[4096], Bh[4096], Bl[4096];
  const int tid = threadIdx.x;
  const int w = tid >> 6, lane = tid & 63;
  const int m = lane & 15, quad = lane >> 4;
  const int wm = w >> 1, wn = w & 1;
  const int m0 = blockIdx.x * 128, n0 = blockIdx.y * 128;
  const int rl = lane >> 2, bp = lane & 3;
  const int sst = (rl >> 1) & 3;                 // staging swizzle
  const int sa = (quad ^ ((m >> 1) & 3)) * 8;    // fragment-read swizzle

  f32x4 acc[4][4];
  const f32x4 vzero = {0.f, 0.f, 0.f, 0.f};
#pragma unroll
  for (int mt = 0; mt < 4; ++mt)
#pragma unroll
    for (int nt = 0; nt < 4; ++nt) acc[mt][nt] = vzero;

  for (int k0 = 0; k0 < DMODEL; k0 += 32) {
#pragma unroll
    for (int i = 0; i < 2; ++i) {
      int cc = w * 2 + i;
      int row = cc * 16 + rl;
      int gofs = k0 + ((bp ^ sst) << 3);
      async_ld16(&Ah[cc * 512], xh + (m0 + row) * DMODEL + gofs);
      async_ld16(&Al[cc * 512], xl + (m0 + row) * DMODEL + gofs);
      async_ld16(&Bh[cc * 512], wh + (n0 + row) * DMODEL + gofs);
      async_ld16(&Bl[cc * 512], wl + (n0 + row) * DMODEL + gofs);
    }
    __syncthreads();
    bf16x8 afh[4], afl[4], bfh[4], bfl[4];
#pragma unroll
    for (int t = 0; t < 4; ++t) {
      int ra = (wm * 64 + t * 16 + m) * 32 + sa;
      afh[t] = *(const bf16x8*)&Ah[ra];
      afl[t] = *(const bf16x8*)&Al[ra];
      int rb = (wn * 64 + t * 16 + m) * 32 + sa;
      bfh[t] = *(const bf16x8*)&Bh[rb];
      bfl[t] = *(const bf16x8*)&Bl[rb];
    }
#pragma unroll
    for (int mt = 0; mt < 4; ++mt)
#pragma unroll
      for (int nt = 0; nt < 4; ++nt) {
        acc[mt][nt] = MFMA(afh[mt], bfh[nt], acc[mt][nt]);
        acc[mt][nt] = MFMA(afh[mt], bfl[nt], acc[mt][nt]);
        acc[mt][nt] = MFMA(afl[mt], bfh[nt], acc[mt][nt]);
      }
    __syncthreads();
  }
  // epilogue: bias, split/convert, scatter
#pragma unroll
  for (int mt = 0; mt < 4; ++mt) {
#pragma unroll
    for (int rg = 0; rg < 4; ++rg) {
      int grow = m0 + wm * 64 + mt * 16 + quad * 4 + rg;
      int bb = grow >> 11, s = grow & (S_LEN - 1);
#pragma unroll
      for (int nt = 0; nt < 4; ++nt) {
        int e = n0 + wn * 64 + nt * 16 + m;
        float val = acc[mt][nt][rg] + bias[e];
        int h = e / 192;
        int r = e - h * 192;
        int d = r & 63;
        int bh = bb * NH + h;
        if (r < 64) {
          u16 hi, lo;
          split_bf16(val, hi, lo);
          int off = (bh * S_LEN + s) * HDIM + d;
          Qhi[off] = hi; Qlo[off] = lo;
        } else if (r < 128) {
          u16 hi, lo;
          split_bf16(val, hi, lo);
          int off = (bh * S_LEN + s) * HDIM + d;
          Khi[off] = hi; Klo[off] = lo;
        } else {
          Vt[(bh * HDIM + d) * S_LEN + s] = f2h_bits(val);
        }
      }
    }
  }
}

// ---------------- Output projection GEMM (split-bf16 MFMA, 3-term) --------
__global__ __launch_bounds__(256) void o_gemm_mfma(
    const u16* __restrict__ valh, const u16* __restrict__ vall,
    const float* __restrict__ ow, const float* __restrict__ bias,
    float* __restrict__ out) {
  __shared__ __align__(16) u16 Ah[4096], Al[4096], Bh[4096], Bl[4096];
  const int tid = threadIdx.x;
  const int w = tid >> 6, lane = tid & 63;
  const int m = lane & 15, quad = lane >> 4;
  const int wm = w >> 1, wn = w & 1;
  const int m0 = blockIdx.x * 128, n0 = blockIdx.y * 128;
  const int rl = lane >> 2, bp = lane & 3;
  const int sst = (rl >> 1) & 3;
  const int sa = (quad ^ ((m >> 1) & 3)) * 8;
  const int rB = tid >> 1, hf = tid & 1;
  const int sB = (rB >> 1) & 3;

  f32x4 acc[4][4];
  const f32x4 vzero = {0.f, 0.f, 0.f, 0.f};
#pragma unroll
  for (int mt = 0; mt < 4; ++mt)
#pragma unroll
    for (int nt = 0; nt < 4; ++nt) acc[mt][nt] = vzero;

  for (int k0 = 0; k0 < DMODEL; k0 += 32) {
#pragma unroll
    for (int i = 0; i < 2; ++i) {
      int cc = w * 2 + i;
      int row = cc * 16 + rl;
      int gofs = k0 + ((bp ^ sst) << 3);
      async_ld16(&Ah[cc * 512], valh + (m0 + row) * DMODEL + gofs);
      async_ld16(&Al[cc * 512], vall + (m0 + row) * DMODEL + gofs);
    }
    {
      const float* src = ow + (n0 + rB) * DMODEL + k0 + hf * 16;
      float tmp[16];
      *(float4*)&tmp[0] = *(const float4*)(src);
      *(float4*)&tmp[4] = *(const float4*)(src + 4);
      *(float4*)&tmp[8] = *(const float4*)(src + 8);
      *(float4*)&tmp[12] = *(const float4*)(src + 12);
      u16 hbuf[16], lbuf[16];
#pragma unroll
      for (int ii = 0; ii < 16; ++ii) split_bf16(tmp[ii], hbuf[ii], lbuf[ii]);
#pragma unroll
      for (int j = 0; j < 2; ++j) {
        int bs = ((2 * hf + j) ^ sB) * 8;
        bf16x8 hv, lv;
#pragma unroll
        for (int q2 = 0; q2 < 8; ++q2) {
          hv[q2] = (short)hbuf[j * 8 + q2];
          lv[q2] = (short)lbuf[j * 8 + q2];
        }
        *(bf16x8*)&Bh[rB * 32 + bs] = hv;
        *(bf16x8*)&Bl[rB * 32 + bs] = lv;
      }
    }
    __syncthreads();
    bf16x8 afh[4], afl[4], bfh[4], bfl[4];
#pragma unroll
    for (int t = 0; t < 4; ++t) {
      int ra = (wm * 64 + t * 16 + m) * 32 + sa;
      afh[t] = *(const bf16x8*)&Ah[ra];
      afl[t] = *(const bf16x8*)&Al[ra];
      int rb = (wn * 64 + t * 16 + m) * 32 + sa;
      bfh[t] = *(const bf16x8*)&Bh[rb];
      bfl[t] = *(const bf16x8*)&Bl[rb];
    }
#pragma unroll
    for (int mt = 0; mt < 4; ++mt)
#pragma unroll
      for (int nt = 0; nt < 4; ++nt) {
        acc[mt][nt] = MFMA(afh[mt], bfh[nt], acc[mt][nt]);
        acc[mt][nt] = MFMA(afh[mt], bfl[nt], acc[mt][nt]);
        acc[mt][nt] = MFMA(afl[mt], bfh[nt], acc[mt][nt]);
      }
    __syncthreads();
  }
#pragma unroll
  for (int mt = 0; mt < 4; ++mt) {
#pragma unroll
    for (int rg = 0; rg < 4; ++rg) {
      int grow = m0 + wm * 64 + mt * 16 + quad * 4 + rg;
#pragma unroll
      for (int nt = 0; nt < 4; ++nt) {
        int e = n0 + wn * 64 + nt * 16 + m;
        out[(size_t)grow * DMODEL + e] = acc[mt][nt][rg] + bias[e];
      }
    }
  }
}

// Per-(b,h) column sums of V (fp16 transposed), for all-pruned fallback.
__global__ __launch_bounds__(256) void vsum_kernel(const u16* __restrict__ Vt,
                                                   float* __restrict__ vsum) {
  const int bh = blockIdx.x;
  const int tid = threadIdx.x;
  const int d = tid >> 2, part = tid & 3;
  int base = (bh * HDIM + d) * S_LEN + part * 512;
  float s = 0.f;
  for (int k = 0; k < 512; k += 8) {
    f16x8 vv = *(const f16x8*)(Vt + base + k);
#pragma unroll
    for (int j = 0; j < 8; ++j) s += (float)vv[j];
  }
  __shared__ float red[64][4];
  red[d][part] = s;
  __syncthreads();
  if (part == 0)
    vsum[bh * HDIM + d] = red[d][0] + red[d][1] + red[d][2] + red[d][3];
}

// Fused two-pass pruned attention. QK^T: split-bf16 4-term (logits identical
// to prior passing kernel). PV: single-fp16 P and V via f16 MFMA; Z2 uses the
// fp16-rounded p so output is an exact weighted average. No max subtraction
// (logits bounded). 48KB LDS -> 3 blocks/CU.
__global__ __launch_bounds__(256) void attn_mfma_kernel(
    const u16* __restrict__ Qhi, const u16* __restrict__ Qlo,
    const u16* __restrict__ Khi, const u16* __restrict__ Klo,
    const u16* __restrict__ Vt, const float* __restrict__ thr,
    const float* __restrict__ vsum, u16* __restrict__ valh,
    u16* __restrict__ vall) {
  const int blk = blockIdx.x;
  const int qt = blk & 31, bh = blk >> 5;
  const int h = bh & (NH - 1), bb = bh >> 4;
  const int tid = threadIdx.x;
  const int w = tid >> 6, lane = tid & 63;
  const int m = lane & 15, quad = lane >> 4;
  const int rsub = lane >> 3;                    // 0..7: row within 8-row chunk
  const int bsw = (lane & 7) ^ rsub;             // swizzled 16B-block index

  // 48KB LDS: K bf16 hi/lo double-buffered (32K), V fp16 (8K), P fp16 (8K)
  __shared__ __align__(16) u16 Kh_s[2][4096];
  __shared__ __align__(16) u16 Kl_s[2][4096];
  __shared__ __align__(16) u16 Vs_s[4096];
  __shared__ __align__(16) u16 Pf_s[4][16][64];

  // persistent Q fragments (A-operand: A[m=lane&15][k=quad*8+j])
  const int qoff = (bh * S_LEN + qt * 64 + w * 16 + m) * HDIM + quad * 8;
  const bf16x8 aQh0 = *(const bf16x8*)(Qhi + qoff);
  const bf16x8 aQh1 = *(const bf16x8*)(Qhi + qoff + 32);
  const bf16x8 aQl0 = *(const bf16x8*)(Qlo + qoff);
  const bf16x8 aQl1 = *(const bf16x8*)(Qlo + qoff + 32);

  const u16* KhT = Khi + bh * S_LEN * HDIM;
  const u16* KlT = Klo + bh * S_LEN * HDIM;
  const u16* VtT = Vt + bh * HDIM * S_LEN;
  const float th = thr[h];

  // swizzled read offsets (within a 64-short row; depends only on lane)
  const int s0 = (quad ^ (m & 7)) * 8;
  const int s1 = ((4 + quad) ^ (m & 7)) * 8;

  float Zr[4], Z2r[4], tzr[4];
#pragma unroll
  for (int r = 0; r < 4; ++r) { Zr[r] = 0.f; Z2r[r] = 0.f; }

  const f32x4 vzero = {0.f, 0.f, 0.f, 0.f};

  // stage helpers: each wave stages chunks {2w, 2w+1} of each tile
#define STAGE_K(bufi, t)                                                     \
  {                                                                          \
    const u16* gh = KhT + (t) * 64 * 64;                                     \
    const u16* gl = KlT + (t) * 64 * 64;                                     \
    _Pragma("unroll") for (int i = 0; i < 2; ++i) {                          \
      int c = w * 2 + i;                                                     \
      int row = c * 8 + rsub;                                                \
      async_ld16(&Kh_s[bufi][c * 512], gh + row * 64 + bsw * 8);             \
      async_ld16(&Kl_s[bufi][c * 512], gl + row * 64 + bsw * 8);             \
    }                                                                        \
  }
#define STAGE_V(t)                                                           \
  {                                                                          \
    _Pragma("unroll") for (int i = 0; i < 2; ++i) {                          \
      int c = w * 2 + i;                                                     \
      int row = c * 8 + rsub;                                                \
      async_ld16(&Vs_s[c * 512], VtT + row * 2048 + (t) * 64 + bsw * 8);     \
    }                                                                        \
  }

  // ------- pass 1: denominator Z (lane-local, no cross-lane per tile) -----
  STAGE_K(0, 0);
  __syncthreads();
  for (int t = 0; t < 32; ++t) {
    const int cur = t & 1;
    if (t < 31) STAGE_K(cur ^ 1, t + 1);
    f32x4 acc[4];
#pragma unroll
    for (int nt = 0; nt < 4; ++nt) acc[nt] = vzero;
#pragma unroll
    for (int nt = 0; nt < 4; ++nt) {
      const int ro = (nt * 16 + m) * 64;
      bf16x8 kh0 = *(const bf16x8*)&Kh_s[cur][ro + s0];
      bf16x8 kh1 = *(const bf16x8*)&Kh_s[cur][ro + s1];
      bf16x8 kl0 = *(const bf16x8*)&Kl_s[cur][ro + s0];
      bf16x8 kl1 = *(const bf16x8*)&Kl_s[cur][ro + s1];
      acc[nt] = MFMA(aQh0, kh0, acc[nt]);
      acc[nt] = MFMA(aQh1, kh1, acc[nt]);
      acc[nt] = MFMA(aQh0, kl0, acc[nt]);
      acc[nt] = MFMA(aQh1, kl1, acc[nt]);
      acc[nt] = MFMA(aQl0, kh0, acc[nt]);
      acc[nt] = MFMA(aQl1, kh1, acc[nt]);
      acc[nt] = MFMA(aQl0, kl0, acc[nt]);
      acc[nt] = MFMA(aQl1, kl1, acc[nt]);
    }
#pragma unroll
    for (int r = 0; r < 4; ++r) {
      Zr[r] += __expf(acc[0][r] * SCALE) + __expf(acc[1][r] * SCALE) +
               __expf(acc[2][r] * SCALE) + __expf(acc[3][r] * SCALE);
    }
    __syncthreads();
  }
#pragma unroll
  for (int r = 0; r < 4; ++r) tzr[r] = th * qredsum(Zr[r]);

  // ---------------- pass 2: masked (pruned) softmax + PV ----------------
  f32x4 oacc[4];
#pragma unroll
  for (int nt = 0; nt < 4; ++nt) oacc[nt] = vzero;

  STAGE_K(0, 0);
  __syncthreads();
  for (int t = 0; t < 32; ++t) {
    const int cur = t & 1;
    STAGE_V(t);
    if (t < 31) STAGE_K(cur ^ 1, t + 1);
    f32x4 acc[4];
#pragma unroll
    for (int nt = 0; nt < 4; ++nt) acc[nt] = vzero;
#pragma unroll
    for (int nt = 0; nt < 4; ++nt) {
      const int ro = (nt * 16 + m) * 64;
      bf16x8 kh0 = *(const bf16x8*)&Kh_s[cur][ro + s0];
      bf16x8 kh1 = *(const bf16x8*)&Kh_s[cur][ro + s1];
      bf16x8 kl0 = *(const bf16x8*)&Kl_s[cur][ro + s0];
      bf16x8 kl1 = *(const bf16x8*)&Kl_s[cur][ro + s1];
      acc[nt] = MFMA(aQh0, kh0, acc[nt]);
      acc[nt] = MFMA(aQh1, kh1, acc[nt]);
      acc[nt] = MFMA(aQh0, kl0, acc[nt]);
      acc[nt] = MFMA(aQh1, kl1, acc[nt]);
      acc[nt] = MFMA(aQl0, kh0, acc[nt]);
      acc[nt] = MFMA(aQl1, kh1, acc[nt]);
      acc[nt] = MFMA(aQl0, kl0, acc[nt]);
      acc[nt] = MFMA(aQl1, kl1, acc[nt]);
    }
    // prune + stage P (fp16) into xor-swizzled per-wave LDS
#pragma unroll
    for (int r = 0; r < 4; ++r) {
      int row = quad * 4 + r;
      float psum = 0.f;
#pragma unroll
      for (int nt = 0; nt < 4; ++nt) {
        float pu = __expf(acc[nt][r] * SCALE);
        float p = (pu > tzr[r]) ? pu : 0.f;
        _Float16 p16 = (_Float16)p;
        psum += (float)p16;  // denominator sees the same rounding as PV
        int col = nt * 16 + m;
        int cs = (((col >> 3) ^ (row & 7)) << 3) | (col & 7);
        Pf_s[w][row][cs] = *(u16*)&p16;
      }
      Z2r[r] += psum;  // lane-local partial; reduced once in epilogue
    }
    __syncthreads();  // V(t) (and K(t+1)) staged; P visible (per-wave anyway)
    // P A-fragments from swizzled LDS (conflict-free b128)
    f16x8 aP0 = *(const f16x8*)&Pf_s[w][m][s0];
    f16x8 aP1 = *(const f16x8*)&Pf_s[w][m][s1];
    // PV: B-operand from LDS-staged transposed fp16 V (B[n=d][k=key])
#pragma unroll
    for (int nt = 0; nt < 4; ++nt) {
      const int ro = (nt * 16 + m) * 64;
      f16x8 vv0 = *(const f16x8*)&Vs_s[ro + s0];
      f16x8 vv1 = *(const f16x8*)&Vs_s[ro + s1];
      oacc[nt] = MFMA16(aP0, vv0, oacc[nt]);
      oacc[nt] = MFMA16(aP1, vv1, oacc[nt]);
    }
    __syncthreads();  // all waves done with V buf / K[cur] before restage
  }

  // ---------------- epilogue: normalize (or uniform fallback), write -------
#pragma unroll
  for (int r = 0; r < 4; ++r) {
    float z2 = qredsum(Z2r[r]);
    float invz = (z2 > 0.f) ? (1.f / z2) : 0.f;
    int srow = qt * 64 + w * 16 + quad * 4 + r;
#pragma unroll
    for (int nt = 0; nt < 4; ++nt) {
      float vs = vsum[bh * HDIM + nt * 16 + m];
      float o = (z2 > 0.f) ? (oacc[nt][r] * invz) : (vs * (1.0f / S_LEN));
      int idx = (bb * S_LEN + srow) * DMODEL + h * HDIM + nt * 16 + m;
      u16 hi, lo;
      split_bf16(o, hi, lo);
      valh[idx] = hi;
      vall[idx] = lo;
    }
  }
}

extern "C" void kernel_launch(void* const* d_in, const int* in_sizes, int n_in,
                              void* d_out, int out_size, void* d_ws, size_t ws_size,
                              hipStream_t stream) {
  const float* x = (const float*)d_in[0];
  const float* thresholds = (const float*)d_in[1];
  const float* qkv_w = (const float*)d_in[2];
  const float* qkv_b = (const float*)d_in[3];
  const float* o_w = (const float*)d_in[4];
  const float* o_b = (const float*)d_in[5];

  const size_t NBH = (size_t)BATCH * NH * S_LEN * HDIM;  // 4194304
  u16* base = (u16*)d_ws;
  u16* Qhi = base;
  u16* Qlo = base + NBH;
  u16* Khi = base + 2 * NBH;
  u16* Klo = base + 3 * NBH;
  u16* Vt = base + 4 * NBH;                // fp16 single, transposed
  float* vsum = (float*)(base + 5 * NBH);  // 2048 floats
  u16* R1 = (u16*)(vsum + 2048);           // 8M u16: x splits, then values
  u16* xh = R1;
  u16* xl = R1 + NBH;
  u16* valh = R1;       // aliases xh/xl after qkv_gemm is done with x
  u16* vall = R1 + NBH;
  // qkv_w splits live in d_out (dead by the time o_gemm writes the output)
  u16* wh = (u16*)d_out;
  u16* wl = wh + (size_t)3 * DMODEL * DMODEL;

  split_pair_kernel<<<4096, 256, 0, stream>>>(x, xh, xl, (int)NBH);
  split_pair_kernel<<<3072, 256, 0, stream>>>(qkv_w, wh, wl, 3 * DMODEL * DMODEL);
  dim3 g1(32, 24);
  qkv_gemm_mfma<<<g1, 256, 0, stream>>>(xh, xl, wh, wl, qkv_b, Qhi, Qlo, Khi,
                                        Klo, Vt);
  vsum_kernel<<<BATCH * NH, 256, 0, stream>>>(Vt, vsum);
  attn_mfma_kernel<<<BATCH * NH * (S_LEN / 64), 256, 0, stream>>>(
      Qhi, Qlo, Khi, Klo, Vt, thresholds, vsum, valh, vall);
  dim3 g3(32, 8);
  o_gemm_mfma<<<g3, 256, 0, stream>>>(valh, vall, o_w, o_b, (float*)d_out);
}